// Round 1
// baseline (10020.991 us; speedup 1.0000x reference)
//
#include <hip/hip_runtime.h>
#include <math.h>

#define LRELU_SLOPE 0.2f
#define BN_EPS 1e-5f

// ---------------------------------------------------------------------------
// conv_down: Conv2d(k=4, s=2, p=1, bias=False), optional fused LeakyReLU.
// in:  [B, Cin, IH, IW]   w: [Cout, Cin, 4, 4]   out: [B, Cout, OH, OW]
// grid: (ceil(OH*OW/256), Cout, B), block 256, dyn LDS = Cin*16 floats
// ---------------------------------------------------------------------------
__global__ __launch_bounds__(256) void conv_down_k(
    const float* __restrict__ in, const float* __restrict__ w,
    float* __restrict__ out,
    int B, int Cin, int IH, int IW, int Cout, int OH, int OW, int act)
{
    extern __shared__ float wl[];  // [Cin][16]
    const int co = blockIdx.y;
    const int b  = blockIdx.z;
    const int tid = threadIdx.x;
    const int nw = Cin * 16;
    for (int i = tid; i < nw; i += 256) wl[i] = w[(size_t)co * nw + i];
    __syncthreads();

    const int opix = blockIdx.x * 256 + tid;
    if (opix >= OH * OW) return;
    const int oy = opix / OW, ox = opix - oy * OW;
    const int iy0 = 2 * oy - 1, ix0 = 2 * ox - 1;
    const float* ib = in + (size_t)b * Cin * IH * IW;
    const int chs = IH * IW;
    float acc = 0.f;

    if (iy0 >= 0 && iy0 + 3 < IH && ix0 >= 0 && ix0 + 3 < IW) {
        const float* p0 = ib + iy0 * IW + ix0;
        for (int ci = 0; ci < Cin; ++ci) {
            const float* q = p0 + (size_t)ci * chs;
            const float* ww = wl + ci * 16;
#pragma unroll
            for (int ky = 0; ky < 4; ++ky) {
                const float* r = q + ky * IW;
                acc = fmaf(r[0], ww[ky * 4 + 0], acc);
                acc = fmaf(r[1], ww[ky * 4 + 1], acc);
                acc = fmaf(r[2], ww[ky * 4 + 2], acc);
                acc = fmaf(r[3], ww[ky * 4 + 3], acc);
            }
        }
    } else {
        for (int ci = 0; ci < Cin; ++ci) {
            const float* q = ib + (size_t)ci * chs;
            const float* ww = wl + ci * 16;
#pragma unroll
            for (int ky = 0; ky < 4; ++ky) {
                const int y = iy0 + ky;
                if ((unsigned)y >= (unsigned)IH) continue;
#pragma unroll
                for (int kx = 0; kx < 4; ++kx) {
                    const int xx = ix0 + kx;
                    if ((unsigned)xx >= (unsigned)IW) continue;
                    acc = fmaf(q[y * IW + xx], ww[ky * 4 + kx], acc);
                }
            }
        }
    }
    if (act == 1) acc = acc > 0.f ? acc : LRELU_SLOPE * acc;
    out[((size_t)(b * Cout + co) * OH + oy) * OW + ox] = acc;
}

// ---------------------------------------------------------------------------
// conv_up: ConvTranspose2d(k=4, s=2, p=1, bias=False).
// in: [B, Cin, IH, IW]   w (torch layout): [Cin, Cout, 4, 4]   out: [B, Cout, 2IH, 2IW]
// out[y][x] = sum_ci sum_taps in[iy][ix] * w[ci][co][y+1-2iy][x+1-2ix]
// ---------------------------------------------------------------------------
__global__ __launch_bounds__(256) void conv_up_k(
    const float* __restrict__ in, const float* __restrict__ w,
    float* __restrict__ out,
    int B, int Cin, int IH, int IW, int Cout, int OH, int OW)
{
    extern __shared__ float wl[];  // [Cin][16]
    const int co = blockIdx.y;
    const int b  = blockIdx.z;
    const int tid = threadIdx.x;
    for (int i = tid; i < Cin * 16; i += 256) {
        const int ci = i >> 4, k = i & 15;
        wl[i] = w[((size_t)ci * Cout + co) * 16 + k];
    }
    __syncthreads();

    const int opix = blockIdx.x * 256 + tid;
    if (opix >= OH * OW) return;
    const int oy = opix / OW, ox = opix - oy * OW;

    const int iya = (oy + 1) >> 1, kya = (oy + 1) & 1;
    const int iyb = iya - 1,       kyb = kya + 2;
    const int ixa = (ox + 1) >> 1, kxa = (ox + 1) & 1;
    const int ixb = ixa - 1,       kxb = kxa + 2;
    const bool vya = iya < IH, vyb = iyb >= 0;
    const bool vxa = ixa < IW, vxb = ixb >= 0;

    const float* ib = in + (size_t)b * Cin * IH * IW;
    const int chs = IH * IW;
    const int kaa = kya * 4 + kxa, kab = kya * 4 + kxb;
    const int kba = kyb * 4 + kxa, kbb = kyb * 4 + kxb;
    float acc = 0.f;

    if (vya & vyb & vxa & vxb) {
        const int oaa = iya * IW + ixa, oab = iya * IW + ixb;
        const int oba = iyb * IW + ixa, obb = iyb * IW + ixb;
        for (int ci = 0; ci < Cin; ++ci) {
            const float* p = ib + (size_t)ci * chs;
            const float* ww = wl + ci * 16;
            acc = fmaf(p[oaa], ww[kaa], acc);
            acc = fmaf(p[oab], ww[kab], acc);
            acc = fmaf(p[oba], ww[kba], acc);
            acc = fmaf(p[obb], ww[kbb], acc);
        }
    } else {
        const float maa = (vya && vxa) ? 1.f : 0.f;
        const float mab = (vya && vxb) ? 1.f : 0.f;
        const float mba = (vyb && vxa) ? 1.f : 0.f;
        const float mbb = (vyb && vxb) ? 1.f : 0.f;
        const int ya = vya ? iya : 0, yb = vyb ? iyb : 0;
        const int xa = vxa ? ixa : 0, xb = vxb ? ixb : 0;
        const int oaa = ya * IW + xa, oab = ya * IW + xb;
        const int oba = yb * IW + xa, obb = yb * IW + xb;
        for (int ci = 0; ci < Cin; ++ci) {
            const float* p = ib + (size_t)ci * chs;
            const float* ww = wl + ci * 16;
            acc = fmaf(p[oaa] * maa, ww[kaa], acc);
            acc = fmaf(p[oab] * mab, ww[kab], acc);
            acc = fmaf(p[oba] * mba, ww[kba], acc);
            acc = fmaf(p[obb] * mbb, ww[kbb], acc);
        }
    }
    out[((size_t)(b * Cout + co) * OH + oy) * OW + ox] = acc;
}

// ---------------------------------------------------------------------------
// BN stats: one block per channel; biased variance over (N,H,W). double accum.
// ---------------------------------------------------------------------------
__global__ __launch_bounds__(256) void bn_stats_k(
    const float* __restrict__ in, float* __restrict__ mean, float* __restrict__ var,
    int B, int C, int HW)
{
    const int c = blockIdx.x;
    const int tid = threadIdx.x;
    const int n = B * HW;
    double s = 0.0, s2 = 0.0;
    for (int e = tid; e < n; e += 256) {
        const int b = e / HW, pix = e - b * HW;
        const float v = in[((size_t)(b * C + c)) * HW + pix];
        s += v; s2 += (double)v * v;
    }
    __shared__ double sh[256], sh2[256];
    sh[tid] = s; sh2[tid] = s2;
    __syncthreads();
    for (int st = 128; st > 0; st >>= 1) {
        if (tid < st) { sh[tid] += sh[tid + st]; sh2[tid] += sh2[tid + st]; }
        __syncthreads();
    }
    if (tid == 0) {
        const double m = sh[0] / n;
        mean[c] = (float)m;
        var[c] = (float)(sh2[0] / n - m * m);
    }
}

// ---------------------------------------------------------------------------
// BN apply + activation (1=lrelu, 2=relu), writing into a concat buffer with
// Ct total channels at channel offset coff.
// ---------------------------------------------------------------------------
__global__ __launch_bounds__(256) void bn_act_k(
    const float* __restrict__ in, const float* __restrict__ mean,
    const float* __restrict__ var, const float* __restrict__ g,
    const float* __restrict__ beta, float* __restrict__ out,
    int B, int C, int HW, int act, int Ct, int coff)
{
    const size_t n = (size_t)B * C * HW;
    for (size_t i = (size_t)blockIdx.x * 256 + threadIdx.x; i < n; i += (size_t)gridDim.x * 256) {
        const int pix = (int)(i % HW);
        const int c = (int)((i / HW) % C);
        const int b = (int)(i / ((size_t)HW * C));
        const float x = in[i];
        float y = (x - mean[c]) * rsqrtf(var[c] + BN_EPS) * g[c] + beta[c];
        if (act == 1) y = y > 0.f ? y : LRELU_SLOPE * y;
        else if (act == 2) y = fmaxf(y, 0.f);
        out[((size_t)(b * Ct + coff + c)) * HW + pix] = y;
    }
}

// ---------------------------------------------------------------------------
// skip copy into concat buffer: dst[b, coff + c, :] = src[b, c, :]
// ---------------------------------------------------------------------------
__global__ __launch_bounds__(256) void copy_skip_k(
    const float* __restrict__ src, float* __restrict__ dst,
    int B, int Cs, int HW, int Ct, int coff)
{
    const size_t n = (size_t)B * Cs * HW;
    const size_t per_b = (size_t)Cs * HW;
    for (size_t i = (size_t)blockIdx.x * 256 + threadIdx.x; i < n; i += (size_t)gridDim.x * 256) {
        const int b = (int)(i / per_b);
        const size_t rem = i - (size_t)b * per_b;
        dst[((size_t)b * Ct + coff) * HW + rem] = src[i];
    }
}

// ---------------------------------------------------------------------------
// final head: nearest-upsample x2 + ZeroPad2d((1,0,1,0)) + Conv2d(k4,s1,p1)
// + bias + tanh, fused.  u: [B,64,128,128]  w: [3,64,4,4]  out: [B,3,256,256]
// Effective: out[y][x] = tanh(b + sum_ci sum_{ky,kx} U[y-2+ky][x-2+kx]*w),
// U[h][w] = u[h>>1][w>>1] for 0<=h,w<256 else 0.
// ---------------------------------------------------------------------------
__global__ __launch_bounds__(256) void final_k(
    const float* __restrict__ u, const float* __restrict__ w,
    const float* __restrict__ bias, float* __restrict__ out, int B)
{
    __shared__ float wl[64 * 16];
    const int co = blockIdx.y, b = blockIdx.z;
    const int tid = threadIdx.x;
    for (int i = tid; i < 64 * 16; i += 256) wl[i] = w[co * 64 * 16 + i];
    __syncthreads();

    const int opix = blockIdx.x * 256 + tid;  // 0..65535
    const int oy = opix >> 8, ox = opix & 255;
    const float* ib = u + (size_t)b * 64 * 128 * 128;
    float acc = bias[co];

    if (oy >= 2 && oy <= 254 && ox >= 2 && ox <= 254) {
        const int r0 = (oy - 2) >> 1, r1 = (oy - 1) >> 1, r2 = oy >> 1, r3 = (oy + 1) >> 1;
        const int c0 = (ox - 2) >> 1, c1 = (ox - 1) >> 1, c2 = ox >> 1, c3 = (ox + 1) >> 1;
        const int o00 = r0 * 128 + c0, o01 = r0 * 128 + c1, o02 = r0 * 128 + c2, o03 = r0 * 128 + c3;
        const int o10 = r1 * 128 + c0, o11 = r1 * 128 + c1, o12 = r1 * 128 + c2, o13 = r1 * 128 + c3;
        const int o20 = r2 * 128 + c0, o21 = r2 * 128 + c1, o22 = r2 * 128 + c2, o23 = r2 * 128 + c3;
        const int o30 = r3 * 128 + c0, o31 = r3 * 128 + c1, o32 = r3 * 128 + c2, o33 = r3 * 128 + c3;
        for (int ci = 0; ci < 64; ++ci) {
            const float* p = ib + ci * 16384;
            const float* ww = wl + ci * 16;
            acc = fmaf(p[o00], ww[0], acc);  acc = fmaf(p[o01], ww[1], acc);
            acc = fmaf(p[o02], ww[2], acc);  acc = fmaf(p[o03], ww[3], acc);
            acc = fmaf(p[o10], ww[4], acc);  acc = fmaf(p[o11], ww[5], acc);
            acc = fmaf(p[o12], ww[6], acc);  acc = fmaf(p[o13], ww[7], acc);
            acc = fmaf(p[o20], ww[8], acc);  acc = fmaf(p[o21], ww[9], acc);
            acc = fmaf(p[o22], ww[10], acc); acc = fmaf(p[o23], ww[11], acc);
            acc = fmaf(p[o30], ww[12], acc); acc = fmaf(p[o31], ww[13], acc);
            acc = fmaf(p[o32], ww[14], acc); acc = fmaf(p[o33], ww[15], acc);
        }
    } else {
        for (int ci = 0; ci < 64; ++ci) {
            const float* p = ib + ci * 16384;
            const float* ww = wl + ci * 16;
#pragma unroll
            for (int ky = 0; ky < 4; ++ky) {
                const int h = oy - 2 + ky;
                if ((unsigned)h >= 256u) continue;
#pragma unroll
                for (int kx = 0; kx < 4; ++kx) {
                    const int xx = ox - 2 + kx;
                    if ((unsigned)xx >= 256u) continue;
                    acc = fmaf(p[(h >> 1) * 128 + (xx >> 1)], ww[ky * 4 + kx], acc);
                }
            }
        }
    }
    out[((size_t)(b * 3 + co) * 256 + oy) * 256 + ox] = tanhf(acc);
}

// ---------------------------------------------------------------------------
// DFT stage A: Rr[r,n] = sum_w U[r,w]*Wr[n,w]; Ri likewise (fused).
// U: [M,256] rows = (b*3+c)*256 + h.  W*: [256(n),256(w)] row-major.
// grid: (16, M/16), block (16,16)
// ---------------------------------------------------------------------------
__global__ __launch_bounds__(256) void dft_rows_k(
    const float* __restrict__ U, const float* __restrict__ Wr,
    const float* __restrict__ Wi, float* __restrict__ Rr, float* __restrict__ Ri)
{
    __shared__ float Ut[16][17], Wrt[16][17], Wit[16][17];
    const int tx = threadIdx.x, ty = threadIdx.y;
    const int r = blockIdx.y * 16 + ty;
    const int nb = blockIdx.x * 16;
    float sr = 0.f, si = 0.f;
    for (int kk = 0; kk < 256; kk += 16) {
        Ut[ty][tx]  = U[(size_t)r * 256 + kk + tx];
        Wrt[ty][tx] = Wr[(size_t)(nb + ty) * 256 + kk + tx];
        Wit[ty][tx] = Wi[(size_t)(nb + ty) * 256 + kk + tx];
        __syncthreads();
#pragma unroll
        for (int t = 0; t < 16; ++t) {
            const float uv = Ut[ty][t];
            sr = fmaf(uv, Wrt[tx][t], sr);
            si = fmaf(uv, Wit[tx][t], si);
        }
        __syncthreads();
    }
    Rr[(size_t)r * 256 + nb + tx] = sr;
    Ri[(size_t)r * 256 + nb + tx] = si;
}

// ---------------------------------------------------------------------------
// DFT stage B (batched over bc=0..23):
// Cr[m,n] = sum_h Wr[h,m]*Rr[h,n] - Wi[h,m]*Ri[h,n]
// Ci[m,n] = sum_h Wr[h,m]*Ri[h,n] + Wi[h,m]*Rr[h,n]
// res[bc, m, 0:256] = Cr ; res[bc, m, 256:512] = Ci
// grid: (16, 16, 24), block (16,16)
// ---------------------------------------------------------------------------
__global__ __launch_bounds__(256) void dft_cols_k(
    const float* __restrict__ Wr, const float* __restrict__ Wi,
    const float* __restrict__ Rr, const float* __restrict__ Ri,
    float* __restrict__ res)
{
    __shared__ float Wrt[16][17], Wit[16][17], Rrt[16][17], Rit[16][17];
    const int tx = threadIdx.x, ty = threadIdx.y;
    const int bc = blockIdx.z;
    const int mb = blockIdx.y * 16, nb = blockIdx.x * 16;
    float cr = 0.f, ci = 0.f;
    for (int hh = 0; hh < 256; hh += 16) {
        Wrt[ty][tx] = Wr[(size_t)(hh + ty) * 256 + mb + tx];
        Wit[ty][tx] = Wi[(size_t)(hh + ty) * 256 + mb + tx];
        Rrt[ty][tx] = Rr[((size_t)bc * 256 + hh + ty) * 256 + nb + tx];
        Rit[ty][tx] = Ri[((size_t)bc * 256 + hh + ty) * 256 + nb + tx];
        __syncthreads();
#pragma unroll
        for (int t = 0; t < 16; ++t) {
            const float wr = Wrt[t][ty], wi = Wit[t][ty];
            const float rr = Rrt[t][tx], ri = Rit[t][tx];
            cr = fmaf(wr, rr, cr);  cr = fmaf(-wi, ri, cr);
            ci = fmaf(wr, ri, ci);  ci = fmaf(wi, rr, ci);
        }
        __syncthreads();
    }
    const int m = mb + ty, n = nb + tx;
    res[((size_t)bc * 256 + m) * 512 + n] = cr;
    res[((size_t)bc * 256 + m) * 512 + 256 + n] = ci;
}

// ---------------------------------------------------------------------------
// host side
// ---------------------------------------------------------------------------
static inline void take_bn(void* const* d_in, const int* in_sizes, int& i, int C,
                           const float*& g, const float*& b)
{
    if (in_sizes[i] == C) {            // two separate leaves (g, b)
        g = (const float*)d_in[i];
        b = (const float*)d_in[i + 1];
        i += 2;
    } else {                           // concatenated [g; b] of size 2C
        g = (const float*)d_in[i];
        b = g + C;
        i += 1;
    }
}

static inline int nblk(size_t n) { return (int)((n + 255) / 256); }

extern "C" void kernel_launch(void* const* d_in, const int* in_sizes, int n_in,
                              void* d_out, int out_size, void* d_ws, size_t ws_size,
                              hipStream_t stream)
{
    const int B = 8;
    int i = 0;
    const float* x     = (const float*)d_in[i++];
    const float* w_d1  = (const float*)d_in[i++];
    const float* w_d2  = (const float*)d_in[i++];
    const float *g_d2, *b_d2; take_bn(d_in, in_sizes, i, 128, g_d2, b_d2);
    const float* w_d3  = (const float*)d_in[i++];
    const float *g_d3, *b_d3; take_bn(d_in, in_sizes, i, 256, g_d3, b_d3);
    const float* w_d4  = (const float*)d_in[i++];
    const float *g_d4, *b_d4; take_bn(d_in, in_sizes, i, 256, g_d4, b_d4);
    const float* w_d5  = (const float*)d_in[i++];
    const float* w_u1  = (const float*)d_in[i++];
    const float *g_u1, *b_u1; take_bn(d_in, in_sizes, i, 256, g_u1, b_u1);
    const float* w_u2  = (const float*)d_in[i++];
    const float *g_u2, *b_u2; take_bn(d_in, in_sizes, i, 256, g_u2, b_u2);
    const float* w_u3  = (const float*)d_in[i++];
    const float *g_u3, *b_u3; take_bn(d_in, in_sizes, i, 128, g_u3, b_u3);
    const float* w_u4  = (const float*)d_in[i++];
    const float *g_u4, *b_u4; take_bn(d_in, in_sizes, i, 32, g_u4, b_u4);
    const float* w_fin = (const float*)d_in[i++];
    const float* b_fin = (const float*)d_in[i++];
    const float* Wr    = (const float*)d_in[i++];
    const float* Wi    = (const float*)d_in[i++];

    // ---- workspace layout (floats) ----
    float* ws = (float*)d_ws;
    size_t off = 0;
    float* d1   = ws + off; off += (size_t)B * 32 * 128 * 128;   // 4,194,304
    float* d2   = ws + off; off += (size_t)B * 128 * 64 * 64;    // 4,194,304
    float* d3   = ws + off; off += (size_t)B * 256 * 32 * 32;    // 2,097,152
    float* d4   = ws + off; off += (size_t)B * 256 * 16 * 16;    //   524,288
    float* d5   = ws + off; off += (size_t)B * 256 * 8 * 8;      //   131,072
    float* u1b  = ws + off; off += (size_t)B * 512 * 16 * 16;    // 1,048,576
    float* u2b  = ws + off; off += (size_t)B * 512 * 32 * 32;    // 4,194,304
    float* u3b  = ws + off; off += (size_t)B * 256 * 64 * 64;    // 8,388,608
    float* u45b = ws + off; off += (size_t)B * 64 * 128 * 128;   // 8,388,608
    float* tmp  = ws + off; off += (size_t)B * 128 * 64 * 64;    // 4,194,304 (max pre-BN conv out)
    float* bnm  = ws + off; off += 256;
    float* bnv  = ws + off; off += 256;
    // DFT temporaries alias dead decoder buffers (both dead once u_out exists)
    float* Rr_buf = u3b;   // needs 1,572,864 <= 8,388,608
    float* Ri_buf = u45b;  // needs 1,572,864 <= 8,388,608

    float* u_out = (float*)d_out;                       // [8,3,256,256]
    float* res   = u_out + (size_t)B * 3 * 256 * 256;   // [8,3,256,512]

    // ---- encoder ----
    // d1 = lrelu(conv(x))            3 -> 32, 256 -> 128
    conv_down_k<<<dim3(64, 32, B), 256, 3 * 16 * 4, stream>>>(x, w_d1, d1, B, 3, 256, 256, 32, 128, 128, 1);
    // d2 = lrelu(bn(conv(d1)))       32 -> 128, 128 -> 64
    conv_down_k<<<dim3(16, 128, B), 256, 32 * 16 * 4, stream>>>(d1, w_d2, tmp, B, 32, 128, 128, 128, 64, 64, 0);
    bn_stats_k<<<128, 256, 0, stream>>>(tmp, bnm, bnv, B, 128, 64 * 64);
    bn_act_k<<<nblk((size_t)B * 128 * 4096), 256, 0, stream>>>(tmp, bnm, bnv, g_d2, b_d2, d2, B, 128, 4096, 1, 128, 0);
    // d3 = lrelu(bn(conv(d2)))       128 -> 256, 64 -> 32
    conv_down_k<<<dim3(4, 256, B), 256, 128 * 16 * 4, stream>>>(d2, w_d3, tmp, B, 128, 64, 64, 256, 32, 32, 0);
    bn_stats_k<<<256, 256, 0, stream>>>(tmp, bnm, bnv, B, 256, 32 * 32);
    bn_act_k<<<nblk((size_t)B * 256 * 1024), 256, 0, stream>>>(tmp, bnm, bnv, g_d3, b_d3, d3, B, 256, 1024, 1, 256, 0);
    // d4 = lrelu(bn(conv(d3)))       256 -> 256, 32 -> 16
    conv_down_k<<<dim3(1, 256, B), 256, 256 * 16 * 4, stream>>>(d3, w_d4, tmp, B, 256, 32, 32, 256, 16, 16, 0);
    bn_stats_k<<<256, 256, 0, stream>>>(tmp, bnm, bnv, B, 256, 16 * 16);
    bn_act_k<<<nblk((size_t)B * 256 * 256), 256, 0, stream>>>(tmp, bnm, bnv, g_d4, b_d4, d4, B, 256, 256, 1, 256, 0);
    // d5 = lrelu(conv(d4))           256 -> 256, 16 -> 8
    conv_down_k<<<dim3(1, 256, B), 256, 256 * 16 * 4, stream>>>(d4, w_d5, d5, B, 256, 16, 16, 256, 8, 8, 1);

    // ---- decoder ----
    // u1 = [relu(bn(convT(d5))), d4]   256 -> 256, 8 -> 16 ; concat 512ch
    conv_up_k<<<dim3(1, 256, B), 256, 256 * 16 * 4, stream>>>(d5, w_u1, tmp, B, 256, 8, 8, 256, 16, 16);
    bn_stats_k<<<256, 256, 0, stream>>>(tmp, bnm, bnv, B, 256, 256);
    bn_act_k<<<nblk((size_t)B * 256 * 256), 256, 0, stream>>>(tmp, bnm, bnv, g_u1, b_u1, u1b, B, 256, 256, 2, 512, 0);
    copy_skip_k<<<nblk((size_t)B * 256 * 256), 256, 0, stream>>>(d4, u1b, B, 256, 256, 512, 256);
    // u2 = [relu(bn(convT(u1))), d3]   512 -> 256, 16 -> 32 ; concat 512ch
    conv_up_k<<<dim3(4, 256, B), 256, 512 * 16 * 4, stream>>>(u1b, w_u2, tmp, B, 512, 16, 16, 256, 32, 32);
    bn_stats_k<<<256, 256, 0, stream>>>(tmp, bnm, bnv, B, 256, 1024);
    bn_act_k<<<nblk((size_t)B * 256 * 1024), 256, 0, stream>>>(tmp, bnm, bnv, g_u2, b_u2, u2b, B, 256, 1024, 2, 512, 0);
    copy_skip_k<<<nblk((size_t)B * 256 * 1024), 256, 0, stream>>>(d3, u2b, B, 256, 1024, 512, 256);
    // u3 = [relu(bn(convT(u2))), d2]   512 -> 128, 32 -> 64 ; concat 256ch
    conv_up_k<<<dim3(16, 128, B), 256, 512 * 16 * 4, stream>>>(u2b, w_u3, tmp, B, 512, 32, 32, 128, 64, 64);
    bn_stats_k<<<128, 256, 0, stream>>>(tmp, bnm, bnv, B, 128, 4096);
    bn_act_k<<<nblk((size_t)B * 128 * 4096), 256, 0, stream>>>(tmp, bnm, bnv, g_u3, b_u3, u3b, B, 128, 4096, 2, 256, 0);
    copy_skip_k<<<nblk((size_t)B * 128 * 4096), 256, 0, stream>>>(d2, u3b, B, 128, 4096, 256, 128);
    // u45 = [relu(bn(convT(u3))), d1]  256 -> 32, 64 -> 128 ; concat 64ch
    conv_up_k<<<dim3(64, 32, B), 256, 256 * 16 * 4, stream>>>(u3b, w_u4, tmp, B, 256, 64, 64, 32, 128, 128);
    bn_stats_k<<<32, 256, 0, stream>>>(tmp, bnm, bnv, B, 32, 16384);
    bn_act_k<<<nblk((size_t)B * 32 * 16384), 256, 0, stream>>>(tmp, bnm, bnv, g_u4, b_u4, u45b, B, 32, 16384, 2, 64, 0);
    copy_skip_k<<<nblk((size_t)B * 32 * 16384), 256, 0, stream>>>(d1, u45b, B, 32, 16384, 64, 32);

    // ---- final head: upsample + pad + conv + bias + tanh -> u_out ----
    final_k<<<dim3(256, 3, B), 256, 0, stream>>>(u45b, w_fin, b_fin, u_out, B);

    // ---- DFT ----
    dft_rows_k<<<dim3(16, 384), dim3(16, 16), 0, stream>>>(u_out, Wr, Wi, Rr_buf, Ri_buf);
    dft_cols_k<<<dim3(16, 16, 24), dim3(16, 16), 0, stream>>>(Wr, Wi, Rr_buf, Ri_buf, res);
}

// Round 5
// 3399.379 us; speedup vs baseline: 2.9479x; 2.9479x over previous
//
#include <hip/hip_runtime.h>
#include <math.h>

#define LRELU_SLOPE 0.2f
#define BN_EPS 1e-5f

// Weight LDS addressing: per-col stride 20 floats (16B-aligned b128 reads),
// +4-float skew per 8-col group, and a per-cc row stride that ABSORBS the
// accumulated skew (COB8*20 + (COB8/8)*4).  The previous version folded the
// skew into a flat (cc*COB8+col)*20 index, which at COB8=32 made the
// cc->cc+1 gap only 8 floats (< the 16-float tap span) -> LDS overlap
// collision that corrupted d5's weights.  Gap is now 24 for COB8=8/16/32.
#define WROW(COB8) ((COB8) * 20 + ((COB8) >> 3) * 4)
#define WIDX(cc, col, COB8) ((cc) * WROW(COB8) + (col) * 20 + ((col) >> 3) * 4)

// ---------------------------------------------------------------------------
// conv_down_t: Conv2d(k=4,s=2,p=1) with register tiling.
// Each thread: 8 output channels x PX consecutive output pixels.
// Block = PGB * COB threads; tid%PGB = pixel-group, tid/PGB = channel-group.
// in is a concat buffer: channel c lives at (b*inCt + inCoff + c); same for out.
// Weights (OIHW) staged in LDS in CICH-channel chunks.
// ---------------------------------------------------------------------------
template<int PX>
__global__ __launch_bounds__(256) void conv_down_t(
    const float* __restrict__ in, const float* __restrict__ w,
    float* __restrict__ out,
    int B, int Cin, int IH, int IW, int Cout, int OH, int OW,
    int inCt, int inCoff, int outCt, int outCoff,
    int PGB, int CICH, int act)
{
    constexpr int NC = 2 * PX + 2;
    extern __shared__ float wl[];
    const int nthr = blockDim.x;
    const int COB8 = (nthr / PGB) * 8;
    const int tid = threadIdx.x;
    const int pg  = tid % PGB;
    const int cog = tid / PGB;
    const int b   = blockIdx.z;
    const int co_base = blockIdx.y * COB8;

    const int gid = blockIdx.x * PGB + pg;
    const int px0 = gid * PX;
    const int oy = px0 / OW, ox0 = px0 - oy * OW;
    const int iy0 = 2 * oy - 1, ix0 = 2 * ox0 - 1;
    const bool interior = (iy0 >= 0) && (iy0 + 3 < IH) && (ix0 >= 0) && (ix0 + NC - 1 < IW);

    float acc[8][PX];
#pragma unroll
    for (int j = 0; j < 8; ++j)
#pragma unroll
        for (int p = 0; p < PX; ++p) acc[j][p] = 0.f;

    const float* ibase = in + ((size_t)b * inCt + inCoff) * IH * IW;

    for (int ci0 = 0; ci0 < Cin; ci0 += CICH) {
        __syncthreads();
        const int nel = CICH * COB8 * 16;
        for (int idx = tid; idx < nel; idx += nthr) {
            const int t = idx & 15;
            const int rest = idx >> 4;
            const int col = rest % COB8;
            const int cc  = rest / COB8;
            wl[WIDX(cc, col, COB8) + t] =
                w[((size_t)(co_base + col) * Cin + ci0 + cc) * 16 + t];
        }
        __syncthreads();

        for (int cc = 0; cc < CICH; ++cc) {
            const float* q = ibase + (size_t)(ci0 + cc) * IH * IW;
            const float* wc = wl + WIDX(cc, cog * 8, COB8);
#pragma unroll
            for (int ky = 0; ky < 4; ++ky) {
                float v[NC];
                const int ry = iy0 + ky;
                if (interior) {
                    const float* r = q + ry * IW + ix0;
#pragma unroll
                    for (int c = 0; c < NC; ++c) v[c] = r[c];
                } else {
                    const bool vy = (unsigned)ry < (unsigned)IH;
                    const float* r = q + (vy ? ry : 0) * IW;
#pragma unroll
                    for (int c = 0; c < NC; ++c) {
                        const int cx = ix0 + c;
                        const bool ok = vy && ((unsigned)cx < (unsigned)IW);
                        v[c] = ok ? r[cx] : 0.f;
                    }
                }
#pragma unroll
                for (int j = 0; j < 8; ++j) {
                    const float4 wk = *(const float4*)(wc + j * 20 + ky * 4);
#pragma unroll
                    for (int p = 0; p < PX; ++p) {
                        acc[j][p] = fmaf(v[2 * p + 0], wk.x, acc[j][p]);
                        acc[j][p] = fmaf(v[2 * p + 1], wk.y, acc[j][p]);
                        acc[j][p] = fmaf(v[2 * p + 2], wk.z, acc[j][p]);
                        acc[j][p] = fmaf(v[2 * p + 3], wk.w, acc[j][p]);
                    }
                }
            }
        }
    }

    const size_t chs = (size_t)OH * OW;
    float* ob = out + ((size_t)b * outCt + outCoff + co_base + cog * 8) * chs + px0;
#pragma unroll
    for (int j = 0; j < 8; ++j) {
#pragma unroll
        for (int p = 0; p < PX; ++p) {
            float y = acc[j][p];
            if (act == 1) y = y > 0.f ? y : LRELU_SLOPE * y;
            acc[j][p] = y;
        }
        if constexpr (PX == 4) {
            *(float4*)(ob + j * chs) = make_float4(acc[j][0], acc[j][1], acc[j][2], acc[j][3]);
        } else if constexpr (PX == 2) {
            *(float2*)(ob + j * chs) = make_float2(acc[j][0], acc[j][1]);
        } else {
            ob[j * chs] = acc[j][0];
        }
    }
}

// ---------------------------------------------------------------------------
// conv_up_t: ConvTranspose2d(k=4,s=2,p=1) with register tiling.
// Each output pixel uses exactly 2x2 input positions; PX consecutive pixels
// share 2 rows x NC cols of input. Weights in torch [Cin][Cout][4][4] layout.
// PX must be even (ox0 even -> compile-time tap parity).
// ---------------------------------------------------------------------------
template<int PX>
__global__ __launch_bounds__(256) void conv_up_t(
    const float* __restrict__ in, const float* __restrict__ w,
    float* __restrict__ out,
    int B, int Cin, int IH, int IW, int Cout, int OH, int OW,
    int inCt, int inCoff, int outCt, int outCoff,
    int PGB, int CICH)
{
    constexpr int NC = (PX >> 1) + 2;
    extern __shared__ float wl[];
    const int nthr = blockDim.x;
    const int COB8 = (nthr / PGB) * 8;
    const int tid = threadIdx.x;
    const int pg  = tid % PGB;
    const int cog = tid / PGB;
    const int b   = blockIdx.z;
    const int co_base = blockIdx.y * COB8;

    const int gid = blockIdx.x * PGB + pg;
    const int px0 = gid * PX;
    const int oy = px0 / OW, ox0 = px0 - oy * OW;
    const int kya = (oy + 1) & 1, kyb = kya + 2;
    const int iya = (oy + 1) >> 1, iyb = iya - 1;
    const int cb = ((ox0 + 1) >> 1) - 1;
    const bool interior = (iyb >= 0) && (iya < IH) && (cb >= 0) && (cb + NC - 1 < IW);

    float acc[8][PX];
#pragma unroll
    for (int j = 0; j < 8; ++j)
#pragma unroll
        for (int p = 0; p < PX; ++p) acc[j][p] = 0.f;

    const float* ibase = in + ((size_t)b * inCt + inCoff) * IH * IW;

    for (int ci0 = 0; ci0 < Cin; ci0 += CICH) {
        __syncthreads();
        const int nel = CICH * COB8 * 16;
        for (int idx = tid; idx < nel; idx += nthr) {
            const int t = idx & 15;
            const int rest = idx >> 4;
            const int col = rest % COB8;
            const int cc  = rest / COB8;
            wl[WIDX(cc, col, COB8) + t] =
                w[((size_t)(ci0 + cc) * Cout + co_base + col) * 16 + t];
        }
        __syncthreads();

        for (int cc = 0; cc < CICH; ++cc) {
            const float* q = ibase + (size_t)(ci0 + cc) * IH * IW;
            const float* wc = wl + WIDX(cc, cog * 8, COB8);
            float va[NC], vb[NC];
            if (interior) {
                const float* ra = q + iya * IW + cb;
                const float* rb = q + iyb * IW + cb;
#pragma unroll
                for (int c = 0; c < NC; ++c) { va[c] = ra[c]; vb[c] = rb[c]; }
            } else {
                const bool vya = iya < IH, vyb = iyb >= 0;
                const float* ra = q + (vya ? iya : 0) * IW;
                const float* rb = q + (vyb ? iyb : 0) * IW;
#pragma unroll
                for (int c = 0; c < NC; ++c) {
                    const int cx = cb + c;
                    const bool okc = (unsigned)cx < (unsigned)IW;
                    va[c] = (vya && okc) ? ra[cx] : 0.f;
                    vb[c] = (vyb && okc) ? rb[cx] : 0.f;
                }
            }
#pragma unroll
            for (int j = 0; j < 8; ++j) {
                const float4 wA4 = *(const float4*)(wc + j * 20 + kya * 4);
                const float4 wB4 = *(const float4*)(wc + j * 20 + kyb * 4);
                const float wA[4] = {wA4.x, wA4.y, wA4.z, wA4.w};
                const float wB[4] = {wB4.x, wB4.y, wB4.z, wB4.w};
#pragma unroll
                for (int p = 0; p < PX; ++p) {
                    const int la = ((p + 1) >> 1) + 1, lb = la - 1;
                    const int ka = (p + 1) & 1, kb = ka + 2;
                    acc[j][p] = fmaf(va[la], wA[ka], acc[j][p]);
                    acc[j][p] = fmaf(va[lb], wA[kb], acc[j][p]);
                    acc[j][p] = fmaf(vb[la], wB[ka], acc[j][p]);
                    acc[j][p] = fmaf(vb[lb], wB[kb], acc[j][p]);
                }
            }
        }
    }

    const size_t chs = (size_t)OH * OW;
    float* ob = out + ((size_t)b * outCt + outCoff + co_base + cog * 8) * chs + px0;
#pragma unroll
    for (int j = 0; j < 8; ++j) {
        if constexpr (PX == 4) {
            *(float4*)(ob + j * chs) = make_float4(acc[j][0], acc[j][1], acc[j][2], acc[j][3]);
        } else if constexpr (PX == 2) {
            *(float2*)(ob + j * chs) = make_float2(acc[j][0], acc[j][1]);
        } else {
            ob[j * chs] = acc[j][0];
        }
    }
}

// ---------------------------------------------------------------------------
// BN stats: one block per channel; biased variance over (N,H,W). double accum.
// ---------------------------------------------------------------------------
__global__ __launch_bounds__(256) void bn_stats_k(
    const float* __restrict__ in, float* __restrict__ mean, float* __restrict__ var,
    int B, int C, int HW)
{
    const int c = blockIdx.x;
    const int tid = threadIdx.x;
    const int n = B * HW;
    double s = 0.0, s2 = 0.0;
    for (int e = tid; e < n; e += 256) {
        const int b = e / HW, pix = e - b * HW;
        const float v = in[((size_t)(b * C + c)) * HW + pix];
        s += v; s2 += (double)v * v;
    }
    __shared__ double sh[256], sh2[256];
    sh[tid] = s; sh2[tid] = s2;
    __syncthreads();
    for (int st = 128; st > 0; st >>= 1) {
        if (tid < st) { sh[tid] += sh[tid + st]; sh2[tid] += sh2[tid + st]; }
        __syncthreads();
    }
    if (tid == 0) {
        const double m = sh[0] / n;
        mean[c] = (float)m;
        var[c] = (float)(sh2[0] / n - m * m);
    }
}

// ---------------------------------------------------------------------------
// BN apply + activation (1=lrelu, 2=relu) into concat buffer (Ct, coff).
// ---------------------------------------------------------------------------
__global__ __launch_bounds__(256) void bn_act_k(
    const float* __restrict__ in, const float* __restrict__ mean,
    const float* __restrict__ var, const float* __restrict__ g,
    const float* __restrict__ beta, float* __restrict__ out,
    int B, int C, int HW, int act, int Ct, int coff)
{
    const size_t n = (size_t)B * C * HW;
    for (size_t i = (size_t)blockIdx.x * 256 + threadIdx.x; i < n; i += (size_t)gridDim.x * 256) {
        const int pix = (int)(i % HW);
        const int c = (int)((i / HW) % C);
        const int b = (int)(i / ((size_t)HW * C));
        const float x = in[i];
        float y = (x - mean[c]) * rsqrtf(var[c] + BN_EPS) * g[c] + beta[c];
        if (act == 1) y = y > 0.f ? y : LRELU_SLOPE * y;
        else if (act == 2) y = fmaxf(y, 0.f);
        out[((size_t)(b * Ct + coff + c)) * HW + pix] = y;
    }
}

// ---------------------------------------------------------------------------
// final head: nearest-upsample x2 + ZeroPad2d((1,0,1,0)) + Conv2d(k4,s1,p1)
// + bias + tanh, fused; all 3 output channels per thread.
// ---------------------------------------------------------------------------
__global__ __launch_bounds__(256) void final_k(
    const float* __restrict__ u, const float* __restrict__ w,
    const float* __restrict__ bias, float* __restrict__ out, int B)
{
    __shared__ float wl[3 * 64 * 16];
    const int b = blockIdx.z;
    const int tid = threadIdx.x;
    for (int i = tid; i < 3 * 64 * 16; i += 256) wl[i] = w[i];
    __syncthreads();

    const int opix = blockIdx.x * 256 + tid;  // 0..65535
    const int oy = opix >> 8, ox = opix & 255;
    const float* ib = u + (size_t)b * 64 * 128 * 128;
    float acc[3] = {bias[0], bias[1], bias[2]};

    int o[16];
    bool ok[16];
    const int r0 = (oy - 2) >> 1, r1 = (oy - 1) >> 1, r2 = oy >> 1, r3 = (oy + 1) >> 1;
    const int c0 = (ox - 2) >> 1, c1 = (ox - 1) >> 1, c2 = ox >> 1, c3 = (ox + 1) >> 1;
    const int rr[4] = {r0, r1, r2, r3};
    const int cc4[4] = {c0, c1, c2, c3};
    const bool interior = (oy >= 2 && oy <= 254 && ox >= 2 && ox <= 254);
#pragma unroll
    for (int ky = 0; ky < 4; ++ky)
#pragma unroll
        for (int kx = 0; kx < 4; ++kx) {
            const int h = oy - 2 + ky, xx = ox - 2 + kx;
            const bool v = ((unsigned)h < 256u) && ((unsigned)xx < 256u);
            ok[ky * 4 + kx] = v;
            const int rrr = v ? rr[ky] : 0, ccc = v ? cc4[kx] : 0;
            o[ky * 4 + kx] = rrr * 128 + ccc;
        }

    for (int ci = 0; ci < 64; ++ci) {
        const float* p = ib + ci * 16384;
        float v[16];
        if (interior) {
#pragma unroll
            for (int k = 0; k < 16; ++k) v[k] = p[o[k]];
        } else {
#pragma unroll
            for (int k = 0; k < 16; ++k) v[k] = ok[k] ? p[o[k]] : 0.f;
        }
#pragma unroll
        for (int co = 0; co < 3; ++co) {
            const float* wj = wl + (co * 64 + ci) * 16;
            const float4 w0 = *(const float4*)(wj + 0);
            const float4 w1 = *(const float4*)(wj + 4);
            const float4 w2 = *(const float4*)(wj + 8);
            const float4 w3 = *(const float4*)(wj + 12);
            acc[co] = fmaf(v[0], w0.x, acc[co]);  acc[co] = fmaf(v[1], w0.y, acc[co]);
            acc[co] = fmaf(v[2], w0.z, acc[co]);  acc[co] = fmaf(v[3], w0.w, acc[co]);
            acc[co] = fmaf(v[4], w1.x, acc[co]);  acc[co] = fmaf(v[5], w1.y, acc[co]);
            acc[co] = fmaf(v[6], w1.z, acc[co]);  acc[co] = fmaf(v[7], w1.w, acc[co]);
            acc[co] = fmaf(v[8], w2.x, acc[co]);  acc[co] = fmaf(v[9], w2.y, acc[co]);
            acc[co] = fmaf(v[10], w2.z, acc[co]); acc[co] = fmaf(v[11], w2.w, acc[co]);
            acc[co] = fmaf(v[12], w3.x, acc[co]); acc[co] = fmaf(v[13], w3.y, acc[co]);
            acc[co] = fmaf(v[14], w3.z, acc[co]); acc[co] = fmaf(v[15], w3.w, acc[co]);
        }
    }
#pragma unroll
    for (int co = 0; co < 3; ++co)
        out[((size_t)(b * 3 + co) * 256 + oy) * 256 + ox] = tanhf(acc[co]);
}

// ---------------------------------------------------------------------------
// DFT stage A: Rr[r,n] = sum_w U[r,w]*Wr[n,w]; Ri likewise (fused).
// ---------------------------------------------------------------------------
__global__ __launch_bounds__(256) void dft_rows_k(
    const float* __restrict__ U, const float* __restrict__ Wr,
    const float* __restrict__ Wi, float* __restrict__ Rr, float* __restrict__ Ri)
{
    __shared__ float Ut[16][17], Wrt[16][17], Wit[16][17];
    const int tx = threadIdx.x, ty = threadIdx.y;
    const int r = blockIdx.y * 16 + ty;
    const int nb = blockIdx.x * 16;
    float sr = 0.f, si = 0.f;
    for (int kk = 0; kk < 256; kk += 16) {
        Ut[ty][tx]  = U[(size_t)r * 256 + kk + tx];
        Wrt[ty][tx] = Wr[(size_t)(nb + ty) * 256 + kk + tx];
        Wit[ty][tx] = Wi[(size_t)(nb + ty) * 256 + kk + tx];
        __syncthreads();
#pragma unroll
        for (int t = 0; t < 16; ++t) {
            const float uv = Ut[ty][t];
            sr = fmaf(uv, Wrt[tx][t], sr);
            si = fmaf(uv, Wit[tx][t], si);
        }
        __syncthreads();
    }
    Rr[(size_t)r * 256 + nb + tx] = sr;
    Ri[(size_t)r * 256 + nb + tx] = si;
}

// ---------------------------------------------------------------------------
// DFT stage B (batched over bc=0..23)
// ---------------------------------------------------------------------------
__global__ __launch_bounds__(256) void dft_cols_k(
    const float* __restrict__ Wr, const float* __restrict__ Wi,
    const float* __restrict__ Rr, const float* __restrict__ Ri,
    float* __restrict__ res)
{
    __shared__ float Wrt[16][17], Wit[16][17], Rrt[16][17], Rit[16][17];
    const int tx = threadIdx.x, ty = threadIdx.y;
    const int bc = blockIdx.z;
    const int mb = blockIdx.y * 16, nb = blockIdx.x * 16;
    float cr = 0.f, ci = 0.f;
    for (int hh = 0; hh < 256; hh += 16) {
        Wrt[ty][tx] = Wr[(size_t)(hh + ty) * 256 + mb + tx];
        Wit[ty][tx] = Wi[(size_t)(hh + ty) * 256 + mb + tx];
        Rrt[ty][tx] = Rr[((size_t)bc * 256 + hh + ty) * 256 + nb + tx];
        Rit[ty][tx] = Ri[((size_t)bc * 256 + hh + ty) * 256 + nb + tx];
        __syncthreads();
#pragma unroll
        for (int t = 0; t < 16; ++t) {
            const float wr = Wrt[t][ty], wi = Wit[t][ty];
            const float rr = Rrt[t][tx], ri = Rit[t][tx];
            cr = fmaf(wr, rr, cr);  cr = fmaf(-wi, ri, cr);
            ci = fmaf(wr, ri, ci);  ci = fmaf(wi, rr, ci);
        }
        __syncthreads();
    }
    const int m = mb + ty, n = nb + tx;
    res[((size_t)bc * 256 + m) * 512 + n] = cr;
    res[((size_t)bc * 256 + m) * 512 + 256 + n] = ci;
}

// ---------------------------------------------------------------------------
// host side
// ---------------------------------------------------------------------------
static inline void take_bn(void* const* d_in, const int* in_sizes, int& i, int C,
                           const float*& g, const float*& b)
{
    if (in_sizes[i] == C) {
        g = (const float*)d_in[i];
        b = (const float*)d_in[i + 1];
        i += 2;
    } else {
        g = (const float*)d_in[i];
        b = g + C;
        i += 1;
    }
}

static inline int nblk(size_t n) { return (int)((n + 255) / 256); }
static inline size_t lds_bytes(int cich, int cob8) {
    return (size_t)cich * (cob8 * 20 + (cob8 / 8) * 4) * 4;
}

extern "C" void kernel_launch(void* const* d_in, const int* in_sizes, int n_in,
                              void* d_out, int out_size, void* d_ws, size_t ws_size,
                              hipStream_t stream)
{
    const int B = 8;
    int i = 0;
    const float* x     = (const float*)d_in[i++];
    const float* w_d1  = (const float*)d_in[i++];
    const float* w_d2  = (const float*)d_in[i++];
    const float *g_d2, *b_d2; take_bn(d_in, in_sizes, i, 128, g_d2, b_d2);
    const float* w_d3  = (const float*)d_in[i++];
    const float *g_d3, *b_d3; take_bn(d_in, in_sizes, i, 256, g_d3, b_d3);
    const float* w_d4  = (const float*)d_in[i++];
    const float *g_d4, *b_d4; take_bn(d_in, in_sizes, i, 256, g_d4, b_d4);
    const float* w_d5  = (const float*)d_in[i++];
    const float* w_u1  = (const float*)d_in[i++];
    const float *g_u1, *b_u1; take_bn(d_in, in_sizes, i, 256, g_u1, b_u1);
    const float* w_u2  = (const float*)d_in[i++];
    const float *g_u2, *b_u2; take_bn(d_in, in_sizes, i, 256, g_u2, b_u2);
    const float* w_u3  = (const float*)d_in[i++];
    const float *g_u3, *b_u3; take_bn(d_in, in_sizes, i, 128, g_u3, b_u3);
    const float* w_u4  = (const float*)d_in[i++];
    const float *g_u4, *b_u4; take_bn(d_in, in_sizes, i, 32, g_u4, b_u4);
    const float* w_fin = (const float*)d_in[i++];
    const float* b_fin = (const float*)d_in[i++];
    const float* Wr    = (const float*)d_in[i++];
    const float* Wi    = (const float*)d_in[i++];

    // ---- workspace layout (floats) ----
    // Encoder outputs are written directly into decoder concat buffers:
    //   d1 -> u45b[:,32:64], d2 -> u3b[:,128:256], d3 -> u2b[:,256:512],
    //   d4 -> u1b[:,256:512].  No skip-copy kernels.
    float* ws = (float*)d_ws;
    size_t off = 0;
    float* u1b  = ws + off; off += (size_t)B * 512 * 16 * 16;    // 1,048,576
    float* u2b  = ws + off; off += (size_t)B * 512 * 32 * 32;    // 4,194,304
    float* u3b  = ws + off; off += (size_t)B * 256 * 64 * 64;    // 8,388,608
    float* u45b = ws + off; off += (size_t)B * 64 * 128 * 128;   // 8,388,608
    float* d5   = ws + off; off += (size_t)B * 256 * 8 * 8;      //   131,072
    float* tmp  = ws + off; off += (size_t)B * 128 * 64 * 64;    // 4,194,304
    float* bnm  = ws + off; off += 256;
    float* bnv  = ws + off; off += 256;
    float* Rr_buf = u3b;    // DFT temps alias dead decoder buffers
    float* Ri_buf = u45b;

    float* u_out = (float*)d_out;                       // [8,3,256,256]
    float* res   = u_out + (size_t)B * 3 * 256 * 256;   // [8,3,256,512]

    // ---- encoder ----
    // d1 = lrelu(conv(x)) -> u45b[:,32:]
    conv_down_t<4><<<dim3(16, 4, B), 256, lds_bytes(3, 8), stream>>>(
        x, w_d1, u45b, B, 3, 256, 256, 32, 128, 128, 3, 0, 64, 32, 256, 3, 1);
    // d2 = lrelu(bn(conv(d1))) -> u3b[:,128:]
    conv_down_t<4><<<dim3(4, 16, B), 256, lds_bytes(32, 8), stream>>>(
        u45b, w_d2, tmp, B, 32, 128, 128, 128, 64, 64, 64, 32, 128, 0, 256, 32, 0);
    bn_stats_k<<<128, 256, 0, stream>>>(tmp, bnm, bnv, B, 128, 4096);
    bn_act_k<<<nblk((size_t)B * 128 * 4096), 256, 0, stream>>>(tmp, bnm, bnv, g_d2, b_d2, u3b, B, 128, 4096, 1, 256, 128);
    // d3 = lrelu(bn(conv(d2))) -> u2b[:,256:]
    conv_down_t<4><<<dim3(1, 32, B), 256, lds_bytes(32, 8), stream>>>(
        u3b, w_d3, tmp, B, 128, 64, 64, 256, 32, 32, 256, 128, 256, 0, 256, 32, 0);
    bn_stats_k<<<256, 256, 0, stream>>>(tmp, bnm, bnv, B, 256, 1024);
    bn_act_k<<<nblk((size_t)B * 256 * 1024), 256, 0, stream>>>(tmp, bnm, bnv, g_d3, b_d3, u2b, B, 256, 1024, 1, 512, 256);
    // d4 = lrelu(bn(conv(d3))) -> u1b[:,256:]   (PX=2: 256 px -> 128 groups)
    conv_down_t<2><<<dim3(1, 16, B), 256, lds_bytes(16, 16), stream>>>(
        u2b, w_d4, tmp, B, 256, 32, 32, 256, 16, 16, 512, 256, 256, 0, 128, 16, 0);
    bn_stats_k<<<256, 256, 0, stream>>>(tmp, bnm, bnv, B, 256, 256);
    bn_act_k<<<nblk((size_t)B * 256 * 256), 256, 0, stream>>>(tmp, bnm, bnv, g_d4, b_d4, u1b, B, 256, 256, 1, 512, 256);
    // d5 = lrelu(conv(d4))   (PX=1: 64 px, COB=4)
    conv_down_t<1><<<dim3(1, 8, B), 256, lds_bytes(8, 32), stream>>>(
        u1b, w_d5, d5, B, 256, 16, 16, 256, 8, 8, 512, 256, 256, 0, 64, 8, 1);

    // ---- decoder ----
    // u1 = relu(bn(convT(d5))) -> u1b[:,0:256]   (PX=2: 256 px -> 128 groups, COB=2)
    conv_up_t<2><<<dim3(1, 16, B), 256, lds_bytes(16, 16), stream>>>(
        d5, w_u1, tmp, B, 256, 8, 8, 256, 16, 16, 256, 0, 256, 0, 128, 16);
    bn_stats_k<<<256, 256, 0, stream>>>(tmp, bnm, bnv, B, 256, 256);
    bn_act_k<<<nblk((size_t)B * 256 * 256), 256, 0, stream>>>(tmp, bnm, bnv, g_u1, b_u1, u1b, B, 256, 256, 2, 512, 0);
    // u2 = relu(bn(convT(u1))) -> u2b[:,0:256]
    conv_up_t<4><<<dim3(1, 32, B), 256, lds_bytes(32, 8), stream>>>(
        u1b, w_u2, tmp, B, 512, 16, 16, 256, 32, 32, 512, 0, 256, 0, 256, 32);
    bn_stats_k<<<256, 256, 0, stream>>>(tmp, bnm, bnv, B, 256, 1024);
    bn_act_k<<<nblk((size_t)B * 256 * 1024), 256, 0, stream>>>(tmp, bnm, bnv, g_u2, b_u2, u2b, B, 256, 1024, 2, 512, 0);
    // u3 = relu(bn(convT(u2))) -> u3b[:,0:128]
    conv_up_t<4><<<dim3(4, 16, B), 256, lds_bytes(32, 8), stream>>>(
        u2b, w_u3, tmp, B, 512, 32, 32, 128, 64, 64, 512, 0, 128, 0, 256, 32);
    bn_stats_k<<<128, 256, 0, stream>>>(tmp, bnm, bnv, B, 128, 4096);
    bn_act_k<<<nblk((size_t)B * 128 * 4096), 256, 0, stream>>>(tmp, bnm, bnv, g_u3, b_u3, u3b, B, 128, 4096, 2, 256, 0);
    // u45 = relu(bn(convT(u3))) -> u45b[:,0:32]
    conv_up_t<4><<<dim3(16, 4, B), 256, lds_bytes(32, 8), stream>>>(
        u3b, w_u4, tmp, B, 256, 64, 64, 32, 128, 128, 256, 0, 32, 0, 256, 32);
    bn_stats_k<<<32, 256, 0, stream>>>(tmp, bnm, bnv, B, 32, 16384);
    bn_act_k<<<nblk((size_t)B * 32 * 16384), 256, 0, stream>>>(tmp, bnm, bnv, g_u4, b_u4, u45b, B, 32, 16384, 2, 64, 0);

    // ---- final head ----
    final_k<<<dim3(256, 1, B), 256, 0, stream>>>(u45b, w_fin, b_fin, u_out, B);

    // ---- DFT ----
    dft_rows_k<<<dim3(16, 384), dim3(16, 16), 0, stream>>>(u_out, Wr, Wi, Rr_buf, Ri_buf);
    dft_cols_k<<<dim3(16, 16, 24), dim3(16, 16), 0, stream>>>(Wr, Wi, Rr_buf, Ri_buf, res);
}

// Round 9
// 2164.099 us; speedup vs baseline: 4.6306x; 1.5708x over previous
//
#include <hip/hip_runtime.h>
#include <math.h>

#define LRELU_SLOPE 0.2f
#define BN_EPS 1e-5f

// Weight LDS addressing: per-col stride 20 floats (16B-aligned b128 reads),
// +4-float skew per 8-col group; per-cc row stride absorbs the skew.
#define WROW(COB8) ((COB8) * 20 + ((COB8) >> 3) * 4)
#define WIDX(cc, col, COB8) ((cc) * WROW(COB8) + (col) * 20 + ((col) >> 3) * 4)

// ---------------------------------------------------------------------------
// conv_down_t: Conv2d(k=4,s=2,p=1), register tiled: 8 co x PX px per thread.
// K-split: blockIdx.z = b*CS + s; split s handles ci in [s*Cin, (s+1)*Cin)
// (Cin = per-split count, CinW = full Cin for weight stride) and writes its
// partial to out + s*pstride.  act only valid when CS==1.
// ---------------------------------------------------------------------------
template<int PX>
__global__ __launch_bounds__(256) void conv_down_t(
    const float* __restrict__ in, const float* __restrict__ w,
    float* __restrict__ out,
    int Cin, int CinW, int IH, int IW, int Cout, int OH, int OW,
    int inCt, int inCoff, int outCt, int outCoff,
    int PGB, int CICH, int act, int CS, size_t pstride)
{
    constexpr int NC = 2 * PX + 2;
    extern __shared__ float wl[];
    const int nthr = blockDim.x;
    const int COB8 = (nthr / PGB) * 8;
    const int tid = threadIdx.x;
    const int pg  = tid % PGB;
    const int cog = tid / PGB;
    const int s   = blockIdx.z % CS;
    const int b   = blockIdx.z / CS;
    const int ciBase = s * Cin;
    out += (size_t)s * pstride;
    const int co_base = blockIdx.y * COB8;

    const int gid = blockIdx.x * PGB + pg;
    const int px0 = gid * PX;
    const int oy = px0 / OW, ox0 = px0 - oy * OW;
    const int iy0 = 2 * oy - 1, ix0 = 2 * ox0 - 1;
    const bool interior = (iy0 >= 0) && (iy0 + 3 < IH) && (ix0 >= 0) && (ix0 + NC - 1 < IW);

    float acc[8][PX];
#pragma unroll
    for (int j = 0; j < 8; ++j)
#pragma unroll
        for (int p = 0; p < PX; ++p) acc[j][p] = 0.f;

    const float* ibase = in + ((size_t)b * inCt + inCoff + ciBase) * IH * IW;

    for (int ci0 = 0; ci0 < Cin; ci0 += CICH) {
        __syncthreads();
        const int nel = CICH * COB8 * 16;
        for (int idx = tid; idx < nel; idx += nthr) {
            const int t = idx & 15;
            const int rest = idx >> 4;
            const int col = rest % COB8;
            const int cc  = rest / COB8;
            wl[WIDX(cc, col, COB8) + t] =
                w[((size_t)(co_base + col) * CinW + ciBase + ci0 + cc) * 16 + t];
        }
        __syncthreads();

        for (int cc = 0; cc < CICH; ++cc) {
            const float* q = ibase + (size_t)(ci0 + cc) * IH * IW;
            const float* wc = wl + WIDX(cc, cog * 8, COB8);
#pragma unroll
            for (int ky = 0; ky < 4; ++ky) {
                float v[NC];
                const int ry = iy0 + ky;
                if (interior) {
                    const float* r = q + ry * IW + ix0;
#pragma unroll
                    for (int c = 0; c < NC; ++c) v[c] = r[c];
                } else {
                    const bool vy = (unsigned)ry < (unsigned)IH;
                    const float* r = q + (vy ? ry : 0) * IW;
#pragma unroll
                    for (int c = 0; c < NC; ++c) {
                        const int cx = ix0 + c;
                        const bool ok = vy && ((unsigned)cx < (unsigned)IW);
                        v[c] = ok ? r[cx] : 0.f;
                    }
                }
#pragma unroll
                for (int j = 0; j < 8; ++j) {
                    const float4 wk = *(const float4*)(wc + j * 20 + ky * 4);
#pragma unroll
                    for (int p = 0; p < PX; ++p) {
                        acc[j][p] = fmaf(v[2 * p + 0], wk.x, acc[j][p]);
                        acc[j][p] = fmaf(v[2 * p + 1], wk.y, acc[j][p]);
                        acc[j][p] = fmaf(v[2 * p + 2], wk.z, acc[j][p]);
                        acc[j][p] = fmaf(v[2 * p + 3], wk.w, acc[j][p]);
                    }
                }
            }
        }
    }

    const size_t chs = (size_t)OH * OW;
    float* ob = out + ((size_t)b * outCt + outCoff + co_base + cog * 8) * chs + px0;
#pragma unroll
    for (int j = 0; j < 8; ++j) {
#pragma unroll
        for (int p = 0; p < PX; ++p) {
            float y = acc[j][p];
            if (act == 1) y = y > 0.f ? y : LRELU_SLOPE * y;
            acc[j][p] = y;
        }
        if constexpr (PX == 4) {
            *(float4*)(ob + j * chs) = make_float4(acc[j][0], acc[j][1], acc[j][2], acc[j][3]);
        } else if constexpr (PX == 2) {
            *(float2*)(ob + j * chs) = make_float2(acc[j][0], acc[j][1]);
        } else {
            ob[j * chs] = acc[j][0];
        }
    }
}

// ---------------------------------------------------------------------------
// conv_up_t: ConvTranspose2d(k=4,s=2,p=1), register tiled, with K-split.
// Weights torch layout [CinW][Cout][4][4]; PX even.
// ---------------------------------------------------------------------------
template<int PX>
__global__ __launch_bounds__(256) void conv_up_t(
    const float* __restrict__ in, const float* __restrict__ w,
    float* __restrict__ out,
    int Cin, int IH, int IW, int Cout, int OH, int OW,
    int inCt, int inCoff, int outCt, int outCoff,
    int PGB, int CICH, int CS, size_t pstride)
{
    constexpr int NC = (PX >> 1) + 2;
    extern __shared__ float wl[];
    const int nthr = blockDim.x;
    const int COB8 = (nthr / PGB) * 8;
    const int tid = threadIdx.x;
    const int pg  = tid % PGB;
    const int cog = tid / PGB;
    const int s   = blockIdx.z % CS;
    const int b   = blockIdx.z / CS;
    const int ciBase = s * Cin;
    out += (size_t)s * pstride;
    const int co_base = blockIdx.y * COB8;

    const int gid = blockIdx.x * PGB + pg;
    const int px0 = gid * PX;
    const int oy = px0 / OW, ox0 = px0 - oy * OW;
    const int kya = (oy + 1) & 1, kyb = kya + 2;
    const int iya = (oy + 1) >> 1, iyb = iya - 1;
    const int cb = ((ox0 + 1) >> 1) - 1;
    const bool interior = (iyb >= 0) && (iya < IH) && (cb >= 0) && (cb + NC - 1 < IW);

    float acc[8][PX];
#pragma unroll
    for (int j = 0; j < 8; ++j)
#pragma unroll
        for (int p = 0; p < PX; ++p) acc[j][p] = 0.f;

    const float* ibase = in + ((size_t)b * inCt + inCoff + ciBase) * IH * IW;

    for (int ci0 = 0; ci0 < Cin; ci0 += CICH) {
        __syncthreads();
        const int nel = CICH * COB8 * 16;
        for (int idx = tid; idx < nel; idx += nthr) {
            const int t = idx & 15;
            const int rest = idx >> 4;
            const int col = rest % COB8;
            const int cc  = rest / COB8;
            wl[WIDX(cc, col, COB8) + t] =
                w[((size_t)(ciBase + ci0 + cc) * Cout + co_base + col) * 16 + t];
        }
        __syncthreads();

        for (int cc = 0; cc < CICH; ++cc) {
            const float* q = ibase + (size_t)(ci0 + cc) * IH * IW;
            const float* wc = wl + WIDX(cc, cog * 8, COB8);
            float va[NC], vb[NC];
            if (interior) {
                const float* ra = q + iya * IW + cb;
                const float* rb = q + iyb * IW + cb;
#pragma unroll
                for (int c = 0; c < NC; ++c) { va[c] = ra[c]; vb[c] = rb[c]; }
            } else {
                const bool vya = iya < IH, vyb = iyb >= 0;
                const float* ra = q + (vya ? iya : 0) * IW;
                const float* rb = q + (vyb ? iyb : 0) * IW;
#pragma unroll
                for (int c = 0; c < NC; ++c) {
                    const int cx = cb + c;
                    const bool okc = (unsigned)cx < (unsigned)IW;
                    va[c] = (vya && okc) ? ra[cx] : 0.f;
                    vb[c] = (vyb && okc) ? rb[cx] : 0.f;
                }
            }
#pragma unroll
            for (int j = 0; j < 8; ++j) {
                const float4 wA4 = *(const float4*)(wc + j * 20 + kya * 4);
                const float4 wB4 = *(const float4*)(wc + j * 20 + kyb * 4);
                const float wA[4] = {wA4.x, wA4.y, wA4.z, wA4.w};
                const float wB[4] = {wB4.x, wB4.y, wB4.z, wB4.w};
#pragma unroll
                for (int p = 0; p < PX; ++p) {
                    const int la = ((p + 1) >> 1) + 1, lb = la - 1;
                    const int ka = (p + 1) & 1, kb = ka + 2;
                    acc[j][p] = fmaf(va[la], wA[ka], acc[j][p]);
                    acc[j][p] = fmaf(va[lb], wA[kb], acc[j][p]);
                    acc[j][p] = fmaf(vb[la], wB[ka], acc[j][p]);
                    acc[j][p] = fmaf(vb[lb], wB[kb], acc[j][p]);
                }
            }
        }
    }

    const size_t chs = (size_t)OH * OW;
    float* ob = out + ((size_t)b * outCt + outCoff + co_base + cog * 8) * chs + px0;
#pragma unroll
    for (int j = 0; j < 8; ++j) {
        if constexpr (PX == 4) {
            *(float4*)(ob + j * chs) = make_float4(acc[j][0], acc[j][1], acc[j][2], acc[j][3]);
        } else if constexpr (PX == 2) {
            *(float2*)(ob + j * chs) = make_float2(acc[j][0], acc[j][1]);
        } else {
            ob[j * chs] = acc[j][0];
        }
    }
}

// ---------------------------------------------------------------------------
// BN stats over NS partial tensors (summed on the fly); biased variance.
// ---------------------------------------------------------------------------
__global__ __launch_bounds__(256) void bn_stats_k(
    const float* __restrict__ in, float* __restrict__ mean, float* __restrict__ var,
    int B, int C, int HW, int NS, size_t pstride)
{
    const int c = blockIdx.x;
    const int tid = threadIdx.x;
    const int n = B * HW;
    double s = 0.0, s2 = 0.0;
    for (int e = tid; e < n; e += 256) {
        const int b = e / HW, pix = e - b * HW;
        const size_t idx = ((size_t)(b * C + c)) * HW + pix;
        float v = in[idx];
        for (int p = 1; p < NS; ++p) v += in[(size_t)p * pstride + idx];
        s += v; s2 += (double)v * v;
    }
    __shared__ double sh[256], sh2[256];
    sh[tid] = s; sh2[tid] = s2;
    __syncthreads();
    for (int st = 128; st > 0; st >>= 1) {
        if (tid < st) { sh[tid] += sh[tid + st]; sh2[tid] += sh2[tid + st]; }
        __syncthreads();
    }
    if (tid == 0) {
        const double m = sh[0] / n;
        mean[c] = (float)m;
        var[c] = (float)(sh2[0] / n - m * m);
    }
}

// ---------------------------------------------------------------------------
// BN apply + activation (1=lrelu, 2=relu) into concat buffer (Ct, coff),
// summing NS partials.
// ---------------------------------------------------------------------------
__global__ __launch_bounds__(256) void bn_act_k(
    const float* __restrict__ in, const float* __restrict__ mean,
    const float* __restrict__ var, const float* __restrict__ g,
    const float* __restrict__ beta, float* __restrict__ out,
    int B, int C, int HW, int act, int Ct, int coff, int NS, size_t pstride)
{
    const size_t n = (size_t)B * C * HW;
    for (size_t i = (size_t)blockIdx.x * 256 + threadIdx.x; i < n; i += (size_t)gridDim.x * 256) {
        const int pix = (int)(i % HW);
        const int c = (int)((i / HW) % C);
        const int b = (int)(i / ((size_t)HW * C));
        float x = in[i];
        for (int p = 1; p < NS; ++p) x += in[(size_t)p * pstride + i];
        float y = (x - mean[c]) * rsqrtf(var[c] + BN_EPS) * g[c] + beta[c];
        if (act == 1) y = y > 0.f ? y : LRELU_SLOPE * y;
        else if (act == 2) y = fmaxf(y, 0.f);
        out[((size_t)(b * Ct + coff + c)) * HW + pix] = y;
    }
}

// ---------------------------------------------------------------------------
// combine NS partials + optional lrelu (for non-BN split layers, i.e. d5)
// ---------------------------------------------------------------------------
__global__ __launch_bounds__(256) void combine_act_k(
    const float* __restrict__ in, float* __restrict__ out,
    size_t n, int NS, size_t pstride, int act)
{
    for (size_t i = (size_t)blockIdx.x * 256 + threadIdx.x; i < n; i += (size_t)gridDim.x * 256) {
        float v = in[i];
        for (int p = 1; p < NS; ++p) v += in[(size_t)p * pstride + i];
        if (act == 1) v = v > 0.f ? v : LRELU_SLOPE * v;
        out[i] = v;
    }
}

// ---------------------------------------------------------------------------
// final head: nearest-upsample x2 + ZeroPad2d((1,0,1,0)) + Conv2d(k4,s1,p1)
// + bias + tanh, fused; all 3 output channels per thread.
// ---------------------------------------------------------------------------
__global__ __launch_bounds__(256) void final_k(
    const float* __restrict__ u, const float* __restrict__ w,
    const float* __restrict__ bias, float* __restrict__ out, int B)
{
    __shared__ float wl[3 * 64 * 16];
    const int b = blockIdx.z;
    const int tid = threadIdx.x;
    for (int i = tid; i < 3 * 64 * 16; i += 256) wl[i] = w[i];
    __syncthreads();

    const int opix = blockIdx.x * 256 + tid;  // 0..65535
    const int oy = opix >> 8, ox = opix & 255;
    const float* ib = u + (size_t)b * 64 * 128 * 128;
    float acc[3] = {bias[0], bias[1], bias[2]};

    int o[16];
    bool ok[16];
    const int r0 = (oy - 2) >> 1, r1 = (oy - 1) >> 1, r2 = oy >> 1, r3 = (oy + 1) >> 1;
    const int c0 = (ox - 2) >> 1, c1 = (ox - 1) >> 1, c2 = ox >> 1, c3 = (ox + 1) >> 1;
    const int rr[4] = {r0, r1, r2, r3};
    const int cc4[4] = {c0, c1, c2, c3};
    const bool interior = (oy >= 2 && oy <= 254 && ox >= 2 && ox <= 254);
#pragma unroll
    for (int ky = 0; ky < 4; ++ky)
#pragma unroll
        for (int kx = 0; kx < 4; ++kx) {
            const int h = oy - 2 + ky, xx = ox - 2 + kx;
            const bool v = ((unsigned)h < 256u) && ((unsigned)xx < 256u);
            ok[ky * 4 + kx] = v;
            const int rrr = v ? rr[ky] : 0, ccc = v ? cc4[kx] : 0;
            o[ky * 4 + kx] = rrr * 128 + ccc;
        }

    for (int ci = 0; ci < 64; ++ci) {
        const float* p = ib + ci * 16384;
        float v[16];
        if (interior) {
#pragma unroll
            for (int k = 0; k < 16; ++k) v[k] = p[o[k]];
        } else {
#pragma unroll
            for (int k = 0; k < 16; ++k) v[k] = ok[k] ? p[o[k]] : 0.f;
        }
#pragma unroll
        for (int co = 0; co < 3; ++co) {
            const float* wj = wl + (co * 64 + ci) * 16;
            const float4 w0 = *(const float4*)(wj + 0);
            const float4 w1 = *(const float4*)(wj + 4);
            const float4 w2 = *(const float4*)(wj + 8);
            const float4 w3 = *(const float4*)(wj + 12);
            acc[co] = fmaf(v[0], w0.x, acc[co]);  acc[co] = fmaf(v[1], w0.y, acc[co]);
            acc[co] = fmaf(v[2], w0.z, acc[co]);  acc[co] = fmaf(v[3], w0.w, acc[co]);
            acc[co] = fmaf(v[4], w1.x, acc[co]);  acc[co] = fmaf(v[5], w1.y, acc[co]);
            acc[co] = fmaf(v[6], w1.z, acc[co]);  acc[co] = fmaf(v[7], w1.w, acc[co]);
            acc[co] = fmaf(v[8], w2.x, acc[co]);  acc[co] = fmaf(v[9], w2.y, acc[co]);
            acc[co] = fmaf(v[10], w2.z, acc[co]); acc[co] = fmaf(v[11], w2.w, acc[co]);
            acc[co] = fmaf(v[12], w3.x, acc[co]); acc[co] = fmaf(v[13], w3.y, acc[co]);
            acc[co] = fmaf(v[14], w3.z, acc[co]); acc[co] = fmaf(v[15], w3.w, acc[co]);
        }
    }
#pragma unroll
    for (int co = 0; co < 3; ++co)
        out[((size_t)(b * 3 + co) * 256 + oy) * 256 + ox] = tanhf(acc[co]);
}

// ---------------------------------------------------------------------------
// DFT stage A: Rr[r,n] = sum_w U[r,w]*Wr[n,w]; Ri likewise (fused).
// ---------------------------------------------------------------------------
__global__ __launch_bounds__(256) void dft_rows_k(
    const float* __restrict__ U, const float* __restrict__ Wr,
    const float* __restrict__ Wi, float* __restrict__ Rr, float* __restrict__ Ri)
{
    __shared__ float Ut[16][17], Wrt[16][17], Wit[16][17];
    const int tx = threadIdx.x, ty = threadIdx.y;
    const int r = blockIdx.y * 16 + ty;
    const int nb = blockIdx.x * 16;
    float sr = 0.f, si = 0.f;
    for (int kk = 0; kk < 256; kk += 16) {
        Ut[ty][tx]  = U[(size_t)r * 256 + kk + tx];
        Wrt[ty][tx] = Wr[(size_t)(nb + ty) * 256 + kk + tx];
        Wit[ty][tx] = Wi[(size_t)(nb + ty) * 256 + kk + tx];
        __syncthreads();
#pragma unroll
        for (int t = 0; t < 16; ++t) {
            const float uv = Ut[ty][t];
            sr = fmaf(uv, Wrt[tx][t], sr);
            si = fmaf(uv, Wit[tx][t], si);
        }
        __syncthreads();
    }
    Rr[(size_t)r * 256 + nb + tx] = sr;
    Ri[(size_t)r * 256 + nb + tx] = si;
}

// ---------------------------------------------------------------------------
// DFT stage B (batched over bc=0..23)
// ---------------------------------------------------------------------------
__global__ __launch_bounds__(256) void dft_cols_k(
    const float* __restrict__ Wr, const float* __restrict__ Wi,
    const float* __restrict__ Rr, const float* __restrict__ Ri,
    float* __restrict__ res)
{
    __shared__ float Wrt[16][17], Wit[16][17], Rrt[16][17], Rit[16][17];
    const int tx = threadIdx.x, ty = threadIdx.y;
    const int bc = blockIdx.z;
    const int mb = blockIdx.y * 16, nb = blockIdx.x * 16;
    float cr = 0.f, ci = 0.f;
    for (int hh = 0; hh < 256; hh += 16) {
        Wrt[ty][tx] = Wr[(size_t)(hh + ty) * 256 + mb + tx];
        Wit[ty][tx] = Wi[(size_t)(hh + ty) * 256 + mb + tx];
        Rrt[ty][tx] = Rr[((size_t)bc * 256 + hh + ty) * 256 + nb + tx];
        Rit[ty][tx] = Ri[((size_t)bc * 256 + hh + ty) * 256 + nb + tx];
        __syncthreads();
#pragma unroll
        for (int t = 0; t < 16; ++t) {
            const float wr = Wrt[t][ty], wi = Wit[t][ty];
            const float rr = Rrt[t][tx], ri = Rit[t][tx];
            cr = fmaf(wr, rr, cr);  cr = fmaf(-wi, ri, cr);
            ci = fmaf(wr, ri, ci);  ci = fmaf(wi, rr, ci);
        }
        __syncthreads();
    }
    const int m = mb + ty, n = nb + tx;
    res[((size_t)bc * 256 + m) * 512 + n] = cr;
    res[((size_t)bc * 256 + m) * 512 + 256 + n] = ci;
}

// ---------------------------------------------------------------------------
// host side
// ---------------------------------------------------------------------------
static inline void take_bn(void* const* d_in, const int* in_sizes, int& i, int C,
                           const float*& g, const float*& b)
{
    if (in_sizes[i] == C) {
        g = (const float*)d_in[i];
        b = (const float*)d_in[i + 1];
        i += 2;
    } else {
        g = (const float*)d_in[i];
        b = g + C;
        i += 1;
    }
}

static inline int nblk(size_t n) { return (int)((n + 255) / 256); }
static inline size_t lds_bytes(int cich, int cob8) {
    return (size_t)cich * WROW(cob8) * 4;
}
static inline int pick_cs(int want, size_t out_elems, size_t tmp_cap) {
    int cs = want;
    while (cs > 1 && out_elems * (size_t)cs > tmp_cap) cs >>= 1;
    return cs;
}
static inline int min_i(int a, int b) { return a < b ? a : b; }

extern "C" void kernel_launch(void* const* d_in, const int* in_sizes, int n_in,
                              void* d_out, int out_size, void* d_ws, size_t ws_size,
                              hipStream_t stream)
{
    const int B = 8;
    int i = 0;
    const float* x     = (const float*)d_in[i++];
    const float* w_d1  = (const float*)d_in[i++];
    const float* w_d2  = (const float*)d_in[i++];
    const float *g_d2, *b_d2; take_bn(d_in, in_sizes, i, 128, g_d2, b_d2);
    const float* w_d3  = (const float*)d_in[i++];
    const float *g_d3, *b_d3; take_bn(d_in, in_sizes, i, 256, g_d3, b_d3);
    const float* w_d4  = (const float*)d_in[i++];
    const float *g_d4, *b_d4; take_bn(d_in, in_sizes, i, 256, g_d4, b_d4);
    const float* w_d5  = (const float*)d_in[i++];
    const float* w_u1  = (const float*)d_in[i++];
    const float *g_u1, *b_u1; take_bn(d_in, in_sizes, i, 256, g_u1, b_u1);
    const float* w_u2  = (const float*)d_in[i++];
    const float *g_u2, *b_u2; take_bn(d_in, in_sizes, i, 256, g_u2, b_u2);
    const float* w_u3  = (const float*)d_in[i++];
    const float *g_u3, *b_u3; take_bn(d_in, in_sizes, i, 128, g_u3, b_u3);
    const float* w_u4  = (const float*)d_in[i++];
    const float *g_u4, *b_u4; take_bn(d_in, in_sizes, i, 32, g_u4, b_u4);
    const float* w_fin = (const float*)d_in[i++];
    const float* b_fin = (const float*)d_in[i++];
    const float* Wr    = (const float*)d_in[i++];
    const float* Wi    = (const float*)d_in[i++];

    // ---- workspace layout (floats) ----
    // Encoder outputs go directly into decoder concat buffers:
    //   d1 -> u45b[:,32:64], d2 -> u3b[:,128:256], d3 -> u2b[:,256:512],
    //   d4 -> u1b[:,256:512].
    // tmp holds CS partial tensors per conv (K-split); sized to whatever
    // ws_size allows (>= 4.2M floats guaranteed by round-5's working layout).
    float* ws = (float*)d_ws;
    size_t off = 0;
    float* u1b  = ws + off; off += (size_t)B * 512 * 16 * 16;    // 1,048,576
    float* u2b  = ws + off; off += (size_t)B * 512 * 32 * 32;    // 4,194,304
    float* u3b  = ws + off; off += (size_t)B * 256 * 64 * 64;    // 8,388,608
    float* u45b = ws + off; off += (size_t)B * 64 * 128 * 128;   // 8,388,608
    float* d5   = ws + off; off += (size_t)B * 256 * 8 * 8;      //   131,072
    float* bnm  = ws + off; off += 256;
    float* bnv  = ws + off; off += 256;
    float* tmp  = ws + off;                                      // rest of ws
    size_t tmp_cap = (ws_size / 4 > off) ? (ws_size / 4 - off) : 0;
    if (tmp_cap < 4194304) tmp_cap = 4194304;  // round-5 floor (known to fit)
    if (tmp_cap > 8388608) tmp_cap = 8388608;  // max any layer wants

    float* Rr_buf = u3b;    // DFT temps alias dead decoder buffers
    float* Ri_buf = u45b;

    float* u_out = (float*)d_out;                       // [8,3,256,256]
    float* res   = u_out + (size_t)B * 3 * 256 * 256;   // [8,3,256,512]

    // per-layer split choice (want -> clamped by tmp capacity)
    const size_t oe_d2 = (size_t)B * 128 * 4096;   const int cs_d2 = pick_cs(2, oe_d2, tmp_cap);
    const size_t oe_d3 = (size_t)B * 256 * 1024;   const int cs_d3 = pick_cs(4, oe_d3, tmp_cap);
    const size_t oe_d4 = (size_t)B * 256 * 256;    const int cs_d4 = pick_cs(8, oe_d4, tmp_cap);
    const size_t oe_d5 = (size_t)B * 256 * 64;     const int cs_d5 = pick_cs(8, oe_d5, tmp_cap);
    const size_t oe_u1 = (size_t)B * 256 * 256;    const int cs_u1 = pick_cs(8, oe_u1, tmp_cap);
    const size_t oe_u2 = (size_t)B * 256 * 1024;   const int cs_u2 = pick_cs(4, oe_u2, tmp_cap);
    const size_t oe_u3 = (size_t)B * 128 * 4096;   const int cs_u3 = pick_cs(2, oe_u3, tmp_cap);
    const size_t oe_u4 = (size_t)B * 32 * 16384;   const int cs_u4 = pick_cs(2, oe_u4, tmp_cap);

    // ---- encoder ----
    // d1 = lrelu(conv(x)) -> u45b[:,32:]  (Cin=3, no split)
    conv_down_t<4><<<dim3(16, 4, B), 256, lds_bytes(3, 8), stream>>>(
        x, w_d1, u45b, 3, 3, 256, 256, 32, 128, 128, 3, 0, 64, 32, 256, 3, 1, 1, 0);
    // d2 = lrelu(bn(conv(d1))) -> u3b[:,128:]
    {
        const int cin = 32 / cs_d2, cich = min_i(32, cin);
        conv_down_t<4><<<dim3(4, 16, B * cs_d2), 256, lds_bytes(cich, 8), stream>>>(
            u45b, w_d2, tmp, cin, 32, 128, 128, 128, 64, 64, 64, 32, 128, 0, 256, cich, 0, cs_d2, oe_d2);
        bn_stats_k<<<128, 256, 0, stream>>>(tmp, bnm, bnv, B, 128, 4096, cs_d2, oe_d2);
        bn_act_k<<<nblk(oe_d2), 256, 0, stream>>>(tmp, bnm, bnv, g_d2, b_d2, u3b, B, 128, 4096, 1, 256, 128, cs_d2, oe_d2);
    }
    // d3 = lrelu(bn(conv(d2))) -> u2b[:,256:]
    {
        const int cin = 128 / cs_d3, cich = min_i(32, cin);
        conv_down_t<4><<<dim3(1, 32, B * cs_d3), 256, lds_bytes(cich, 8), stream>>>(
            u3b, w_d3, tmp, cin, 128, 64, 64, 256, 32, 32, 256, 128, 256, 0, 256, cich, 0, cs_d3, oe_d3);
        bn_stats_k<<<256, 256, 0, stream>>>(tmp, bnm, bnv, B, 256, 1024, cs_d3, oe_d3);
        bn_act_k<<<nblk(oe_d3), 256, 0, stream>>>(tmp, bnm, bnv, g_d3, b_d3, u2b, B, 256, 1024, 1, 512, 256, cs_d3, oe_d3);
    }
    // d4 = lrelu(bn(conv(d3))) -> u1b[:,256:]
    {
        const int cin = 256 / cs_d4, cich = min_i(16, cin);
        conv_down_t<2><<<dim3(1, 16, B * cs_d4), 256, lds_bytes(cich, 16), stream>>>(
            u2b, w_d4, tmp, cin, 256, 32, 32, 256, 16, 16, 512, 256, 256, 0, 128, cich, 0, cs_d4, oe_d4);
        bn_stats_k<<<256, 256, 0, stream>>>(tmp, bnm, bnv, B, 256, 256, cs_d4, oe_d4);
        bn_act_k<<<nblk(oe_d4), 256, 0, stream>>>(tmp, bnm, bnv, g_d4, b_d4, u1b, B, 256, 256, 1, 512, 256, cs_d4, oe_d4);
    }
    // d5 = lrelu(conv(d4))  (split partials -> combine_act)
    {
        const int cin = 256 / cs_d5, cich = min_i(8, cin);
        conv_down_t<1><<<dim3(1, 8, B * cs_d5), 256, lds_bytes(cich, 32), stream>>>(
            u1b, w_d5, tmp, cin, 256, 16, 16, 256, 8, 8, 512, 256, 256, 0, 64, cich, 0, cs_d5, oe_d5);
        combine_act_k<<<nblk(oe_d5), 256, 0, stream>>>(tmp, d5, oe_d5, cs_d5, oe_d5, 1);
    }

    // ---- decoder ----
    // u1 = relu(bn(convT(d5))) -> u1b[:,0:256]
    {
        const int cin = 256 / cs_u1, cich = min_i(16, cin);
        conv_up_t<2><<<dim3(1, 16, B * cs_u1), 256, lds_bytes(cich, 16), stream>>>(
            d5, w_u1, tmp, cin, 8, 8, 256, 16, 16, 256, 0, 256, 0, 128, cich, cs_u1, oe_u1);
        bn_stats_k<<<256, 256, 0, stream>>>(tmp, bnm, bnv, B, 256, 256, cs_u1, oe_u1);
        bn_act_k<<<nblk(oe_u1), 256, 0, stream>>>(tmp, bnm, bnv, g_u1, b_u1, u1b, B, 256, 256, 2, 512, 0, cs_u1, oe_u1);
    }
    // u2 = relu(bn(convT(u1))) -> u2b[:,0:256]
    {
        const int cin = 512 / cs_u2, cich = min_i(32, cin);
        conv_up_t<4><<<dim3(1, 32, B * cs_u2), 256, lds_bytes(cich, 8), stream>>>(
            u1b, w_u2, tmp, cin, 16, 16, 256, 32, 32, 512, 0, 256, 0, 256, cich, cs_u2, oe_u2);
        bn_stats_k<<<256, 256, 0, stream>>>(tmp, bnm, bnv, B, 256, 1024, cs_u2, oe_u2);
        bn_act_k<<<nblk(oe_u2), 256, 0, stream>>>(tmp, bnm, bnv, g_u2, b_u2, u2b, B, 256, 1024, 2, 512, 0, cs_u2, oe_u2);
    }
    // u3 = relu(bn(convT(u2))) -> u3b[:,0:128]
    {
        const int cin = 512 / cs_u3, cich = min_i(32, cin);
        conv_up_t<4><<<dim3(4, 16, B * cs_u3), 256, lds_bytes(cich, 8), stream>>>(
            u2b, w_u3, tmp, cin, 32, 32, 128, 64, 64, 512, 0, 128, 0, 256, cich, cs_u3, oe_u3);
        bn_stats_k<<<128, 256, 0, stream>>>(tmp, bnm, bnv, B, 128, 4096, cs_u3, oe_u3);
        bn_act_k<<<nblk(oe_u3), 256, 0, stream>>>(tmp, bnm, bnv, g_u3, b_u3, u3b, B, 128, 4096, 2, 256, 0, cs_u3, oe_u3);
    }
    // u45 = relu(bn(convT(u3))) -> u45b[:,0:32]
    {
        const int cin = 256 / cs_u4, cich = min_i(32, cin);
        conv_up_t<4><<<dim3(16, 4, B * cs_u4), 256, lds_bytes(cich, 8), stream>>>(
            u3b, w_u4, tmp, cin, 64, 64, 32, 128, 128, 256, 0, 32, 0, 256, cich, cs_u4, oe_u4);
        bn_stats_k<<<32, 256, 0, stream>>>(tmp, bnm, bnv, B, 32, 16384, cs_u4, oe_u4);
        bn_act_k<<<nblk(oe_u4), 256, 0, stream>>>(tmp, bnm, bnv, g_u4, b_u4, u45b, B, 32, 16384, 2, 64, 0, cs_u4, oe_u4);
    }

    // ---- final head ----
    final_k<<<dim3(256, 1, B), 256, 0, stream>>>(u45b, w_fin, b_fin, u_out, B);

    // ---- DFT ----
    dft_rows_k<<<dim3(16, 384), dim3(16, 16), 0, stream>>>(u_out, Wr, Wi, Rr_buf, Ri_buf);
    dft_cols_k<<<dim3(16, 16, 24), dim3(16, 16), 0, stream>>>(Wr, Wi, Rr_buf, Ri_buf, res);
}

// Round 10
// 1839.941 us; speedup vs baseline: 5.4464x; 1.1762x over previous
//
#include <hip/hip_runtime.h>
#include <math.h>

#define LRELU_SLOPE 0.2f
#define BN_EPS 1e-5f

// Weight LDS addressing: per-col stride 20 floats (16B-aligned b128 reads),
// +4-float skew per 8-col group; per-cc row stride absorbs the skew.
#define WROW(COB8) ((COB8) * 20 + ((COB8) >> 3) * 4)
#define WIDX(cc, col, COB8) ((cc) * WROW(COB8) + (col) * 20 + ((col) >> 3) * 4)

// ---------------------------------------------------------------------------
// conv_down_t: Conv2d(k=4,s=2,p=1), register tiled: 8 co x PX px per thread.
// K-split: blockIdx.z = b*CS + s; split s handles ci in [s*Cin, (s+1)*Cin)
// and writes its partial to out + s*pstride.  act only valid when CS==1.
// ---------------------------------------------------------------------------
template<int PX>
__global__ __launch_bounds__(256) void conv_down_t(
    const float* __restrict__ in, const float* __restrict__ w,
    float* __restrict__ out,
    int Cin, int CinW, int IH, int IW, int Cout, int OH, int OW,
    int inCt, int inCoff, int outCt, int outCoff,
    int PGB, int CICH, int act, int CS, size_t pstride)
{
    constexpr int NC = 2 * PX + 2;
    extern __shared__ float wl[];
    const int nthr = blockDim.x;
    const int COB8 = (nthr / PGB) * 8;
    const int tid = threadIdx.x;
    const int pg  = tid % PGB;
    const int cog = tid / PGB;
    const int s   = blockIdx.z % CS;
    const int b   = blockIdx.z / CS;
    const int ciBase = s * Cin;
    out += (size_t)s * pstride;
    const int co_base = blockIdx.y * COB8;

    const int gid = blockIdx.x * PGB + pg;
    const int px0 = gid * PX;
    const int oy = px0 / OW, ox0 = px0 - oy * OW;
    const int iy0 = 2 * oy - 1, ix0 = 2 * ox0 - 1;
    const bool interior = (iy0 >= 0) && (iy0 + 3 < IH) && (ix0 >= 0) && (ix0 + NC - 1 < IW);

    float acc[8][PX];
#pragma unroll
    for (int j = 0; j < 8; ++j)
#pragma unroll
        for (int p = 0; p < PX; ++p) acc[j][p] = 0.f;

    const float* ibase = in + ((size_t)b * inCt + inCoff + ciBase) * IH * IW;

    for (int ci0 = 0; ci0 < Cin; ci0 += CICH) {
        __syncthreads();
        const int nel = CICH * COB8 * 16;
        for (int idx = tid; idx < nel; idx += nthr) {
            const int t = idx & 15;
            const int rest = idx >> 4;
            const int col = rest % COB8;
            const int cc  = rest / COB8;
            wl[WIDX(cc, col, COB8) + t] =
                w[((size_t)(co_base + col) * CinW + ciBase + ci0 + cc) * 16 + t];
        }
        __syncthreads();

        for (int cc = 0; cc < CICH; ++cc) {
            const float* q = ibase + (size_t)(ci0 + cc) * IH * IW;
            const float* wc = wl + WIDX(cc, cog * 8, COB8);
#pragma unroll
            for (int ky = 0; ky < 4; ++ky) {
                float v[NC];
                const int ry = iy0 + ky;
                if (interior) {
                    const float* r = q + ry * IW + ix0;
#pragma unroll
                    for (int c = 0; c < NC; ++c) v[c] = r[c];
                } else {
                    const bool vy = (unsigned)ry < (unsigned)IH;
                    const float* r = q + (vy ? ry : 0) * IW;
#pragma unroll
                    for (int c = 0; c < NC; ++c) {
                        const int cx = ix0 + c;
                        const bool ok = vy && ((unsigned)cx < (unsigned)IW);
                        v[c] = ok ? r[cx] : 0.f;
                    }
                }
#pragma unroll
                for (int j = 0; j < 8; ++j) {
                    const float4 wk = *(const float4*)(wc + j * 20 + ky * 4);
#pragma unroll
                    for (int p = 0; p < PX; ++p) {
                        acc[j][p] = fmaf(v[2 * p + 0], wk.x, acc[j][p]);
                        acc[j][p] = fmaf(v[2 * p + 1], wk.y, acc[j][p]);
                        acc[j][p] = fmaf(v[2 * p + 2], wk.z, acc[j][p]);
                        acc[j][p] = fmaf(v[2 * p + 3], wk.w, acc[j][p]);
                    }
                }
            }
        }
    }

    const size_t chs = (size_t)OH * OW;
    float* ob = out + ((size_t)b * outCt + outCoff + co_base + cog * 8) * chs + px0;
#pragma unroll
    for (int j = 0; j < 8; ++j) {
#pragma unroll
        for (int p = 0; p < PX; ++p) {
            float y = acc[j][p];
            if (act == 1) y = y > 0.f ? y : LRELU_SLOPE * y;
            acc[j][p] = y;
        }
        if constexpr (PX == 4) {
            *(float4*)(ob + j * chs) = make_float4(acc[j][0], acc[j][1], acc[j][2], acc[j][3]);
        } else if constexpr (PX == 2) {
            *(float2*)(ob + j * chs) = make_float2(acc[j][0], acc[j][1]);
        } else {
            ob[j * chs] = acc[j][0];
        }
    }
}

// ---------------------------------------------------------------------------
// conv_up_t: ConvTranspose2d(k=4,s=2,p=1), register tiled, with K-split.
// Weights torch layout [CinW][Cout][4][4]; PX even.
// ---------------------------------------------------------------------------
template<int PX>
__global__ __launch_bounds__(256) void conv_up_t(
    const float* __restrict__ in, const float* __restrict__ w,
    float* __restrict__ out,
    int Cin, int IH, int IW, int Cout, int OH, int OW,
    int inCt, int inCoff, int outCt, int outCoff,
    int PGB, int CICH, int CS, size_t pstride)
{
    constexpr int NC = (PX >> 1) + 2;
    extern __shared__ float wl[];
    const int nthr = blockDim.x;
    const int COB8 = (nthr / PGB) * 8;
    const int tid = threadIdx.x;
    const int pg  = tid % PGB;
    const int cog = tid / PGB;
    const int s   = blockIdx.z % CS;
    const int b   = blockIdx.z / CS;
    const int ciBase = s * Cin;
    out += (size_t)s * pstride;
    const int co_base = blockIdx.y * COB8;

    const int gid = blockIdx.x * PGB + pg;
    const int px0 = gid * PX;
    const int oy = px0 / OW, ox0 = px0 - oy * OW;
    const int kya = (oy + 1) & 1, kyb = kya + 2;
    const int iya = (oy + 1) >> 1, iyb = iya - 1;
    const int cb = ((ox0 + 1) >> 1) - 1;
    const bool interior = (iyb >= 0) && (iya < IH) && (cb >= 0) && (cb + NC - 1 < IW);

    float acc[8][PX];
#pragma unroll
    for (int j = 0; j < 8; ++j)
#pragma unroll
        for (int p = 0; p < PX; ++p) acc[j][p] = 0.f;

    const float* ibase = in + ((size_t)b * inCt + inCoff + ciBase) * IH * IW;

    for (int ci0 = 0; ci0 < Cin; ci0 += CICH) {
        __syncthreads();
        const int nel = CICH * COB8 * 16;
        for (int idx = tid; idx < nel; idx += nthr) {
            const int t = idx & 15;
            const int rest = idx >> 4;
            const int col = rest % COB8;
            const int cc  = rest / COB8;
            wl[WIDX(cc, col, COB8) + t] =
                w[((size_t)(ciBase + ci0 + cc) * Cout + co_base + col) * 16 + t];
        }
        __syncthreads();

        for (int cc = 0; cc < CICH; ++cc) {
            const float* q = ibase + (size_t)(ci0 + cc) * IH * IW;
            const float* wc = wl + WIDX(cc, cog * 8, COB8);
            float va[NC], vb[NC];
            if (interior) {
                const float* ra = q + iya * IW + cb;
                const float* rb = q + iyb * IW + cb;
#pragma unroll
                for (int c = 0; c < NC; ++c) { va[c] = ra[c]; vb[c] = rb[c]; }
            } else {
                const bool vya = iya < IH, vyb = iyb >= 0;
                const float* ra = q + (vya ? iya : 0) * IW;
                const float* rb = q + (vyb ? iyb : 0) * IW;
#pragma unroll
                for (int c = 0; c < NC; ++c) {
                    const int cx = cb + c;
                    const bool okc = (unsigned)cx < (unsigned)IW;
                    va[c] = (vya && okc) ? ra[cx] : 0.f;
                    vb[c] = (vyb && okc) ? rb[cx] : 0.f;
                }
            }
#pragma unroll
            for (int j = 0; j < 8; ++j) {
                const float4 wA4 = *(const float4*)(wc + j * 20 + kya * 4);
                const float4 wB4 = *(const float4*)(wc + j * 20 + kyb * 4);
                const float wA[4] = {wA4.x, wA4.y, wA4.z, wA4.w};
                const float wB[4] = {wB4.x, wB4.y, wB4.z, wB4.w};
#pragma unroll
                for (int p = 0; p < PX; ++p) {
                    const int la = ((p + 1) >> 1) + 1, lb = la - 1;
                    const int ka = (p + 1) & 1, kb = ka + 2;
                    acc[j][p] = fmaf(va[la], wA[ka], acc[j][p]);
                    acc[j][p] = fmaf(va[lb], wA[kb], acc[j][p]);
                    acc[j][p] = fmaf(vb[la], wB[ka], acc[j][p]);
                    acc[j][p] = fmaf(vb[lb], wB[kb], acc[j][p]);
                }
            }
        }
    }

    const size_t chs = (size_t)OH * OW;
    float* ob = out + ((size_t)b * outCt + outCoff + co_base + cog * 8) * chs + px0;
#pragma unroll
    for (int j = 0; j < 8; ++j) {
        if constexpr (PX == 4) {
            *(float4*)(ob + j * chs) = make_float4(acc[j][0], acc[j][1], acc[j][2], acc[j][3]);
        } else if constexpr (PX == 2) {
            *(float2*)(ob + j * chs) = make_float2(acc[j][0], acc[j][1]);
        } else {
            ob[j * chs] = acc[j][0];
        }
    }
}

// ---------------------------------------------------------------------------
// BN stats stage 1: grid (C, NB); block reduces its pix-chunk of all B rows
// (float4 loads, NS partials summed per element) into double partials.
// NB must divide HW/4.
// ---------------------------------------------------------------------------
__global__ __launch_bounds__(256) void bn_stats1_k(
    const float* __restrict__ in, double* __restrict__ part,
    int B, int C, int HW, int NS, size_t pstride, int NB)
{
    const int c = blockIdx.x;
    const int chunk = blockIdx.y;
    const int tid = threadIdx.x;
    const int vper = (HW >> 2) / NB;
    const int v0 = chunk * vper, v1 = v0 + vper;
    double s = 0.0, s2 = 0.0;
    for (int b = 0; b < B; ++b) {
        const size_t rowv = (((size_t)b * C + c) * HW) >> 2;
        const float4* p0 = (const float4*)in + rowv;
        for (int v = v0 + tid; v < v1; v += 256) {
            float4 a = p0[v];
            for (int p = 1; p < NS; ++p) {
                const float4* pp = (const float4*)(in + (size_t)p * pstride) + rowv;
                const float4 t4 = pp[v];
                a.x += t4.x; a.y += t4.y; a.z += t4.z; a.w += t4.w;
            }
            s += (double)a.x + a.y + a.z + a.w;
            s2 += (double)a.x * a.x + (double)a.y * a.y + (double)a.z * a.z + (double)a.w * a.w;
        }
    }
    __shared__ double sh[256], sh2[256];
    sh[tid] = s; sh2[tid] = s2;
    __syncthreads();
    for (int st = 128; st > 0; st >>= 1) {
        if (tid < st) { sh[tid] += sh[tid + st]; sh2[tid] += sh2[tid + st]; }
        __syncthreads();
    }
    if (tid == 0) {
        part[(size_t)(c * NB + chunk) * 2 + 0] = sh[0];
        part[(size_t)(c * NB + chunk) * 2 + 1] = sh2[0];
    }
}

// ---------------------------------------------------------------------------
// BN stats stage 2: grid C, 64 lanes; reduce NB partials -> mean/var (biased).
// ---------------------------------------------------------------------------
__global__ __launch_bounds__(64) void bn_stats2_k(
    const double* __restrict__ part, float* __restrict__ mean,
    float* __restrict__ var, int n, int NB)
{
    const int c = blockIdx.x;
    const int t = threadIdx.x;
    double s  = (t < NB) ? part[(size_t)(c * NB + t) * 2 + 0] : 0.0;
    double s2 = (t < NB) ? part[(size_t)(c * NB + t) * 2 + 1] : 0.0;
    for (int o = 32; o > 0; o >>= 1) {
        s  += __shfl_down(s, o, 64);
        s2 += __shfl_down(s2, o, 64);
    }
    if (t == 0) {
        const double m = s / n;
        mean[c] = (float)m;
        var[c] = (float)(s2 / n - m * m);
    }
}

// ---------------------------------------------------------------------------
// BN apply + act (1=lrelu, 2=relu) into concat buffer; one block per (b,c)
// row, float4, channel constants hoisted.  grid = B*C.
// ---------------------------------------------------------------------------
__global__ __launch_bounds__(256) void bn_act_k(
    const float* __restrict__ in, const float* __restrict__ mean,
    const float* __restrict__ var, const float* __restrict__ g,
    const float* __restrict__ beta, float* __restrict__ out,
    int C, int HW, int act, int Ct, int coff, int NS, size_t pstride)
{
    const int bc = blockIdx.x;
    const int c = bc % C, b = bc / C;
    const float sc = rsqrtf(var[c] + BN_EPS) * g[c];
    const float sh = beta[c] - mean[c] * sc;
    const size_t rowv = (((size_t)b * C + c) * HW) >> 2;
    const float4* p0 = (const float4*)in + rowv;
    float4* o4 = (float4*)(out + ((size_t)(b * Ct + coff + c)) * HW);
    const int nv = HW >> 2;
    for (int v = threadIdx.x; v < nv; v += 256) {
        float4 a = p0[v];
        for (int p = 1; p < NS; ++p) {
            const float4* pp = (const float4*)(in + (size_t)p * pstride) + rowv;
            const float4 t4 = pp[v];
            a.x += t4.x; a.y += t4.y; a.z += t4.z; a.w += t4.w;
        }
        a.x = a.x * sc + sh; a.y = a.y * sc + sh;
        a.z = a.z * sc + sh; a.w = a.w * sc + sh;
        if (act == 1) {
            a.x = a.x > 0.f ? a.x : LRELU_SLOPE * a.x;
            a.y = a.y > 0.f ? a.y : LRELU_SLOPE * a.y;
            a.z = a.z > 0.f ? a.z : LRELU_SLOPE * a.z;
            a.w = a.w > 0.f ? a.w : LRELU_SLOPE * a.w;
        } else if (act == 2) {
            a.x = fmaxf(a.x, 0.f); a.y = fmaxf(a.y, 0.f);
            a.z = fmaxf(a.z, 0.f); a.w = fmaxf(a.w, 0.f);
        }
        o4[v] = a;
    }
}

// ---------------------------------------------------------------------------
// combine NS partials + optional lrelu (flat float4; for d5)
// ---------------------------------------------------------------------------
__global__ __launch_bounds__(256) void combine_act_k(
    const float* __restrict__ in, float* __restrict__ out,
    size_t nv, int NS, size_t pstride, int act)
{
    for (size_t v = (size_t)blockIdx.x * 256 + threadIdx.x; v < nv; v += (size_t)gridDim.x * 256) {
        float4 a = ((const float4*)in)[v];
        for (int p = 1; p < NS; ++p) {
            const float4 t4 = ((const float4*)(in + (size_t)p * pstride))[v];
            a.x += t4.x; a.y += t4.y; a.z += t4.z; a.w += t4.w;
        }
        if (act == 1) {
            a.x = a.x > 0.f ? a.x : LRELU_SLOPE * a.x;
            a.y = a.y > 0.f ? a.y : LRELU_SLOPE * a.y;
            a.z = a.z > 0.f ? a.z : LRELU_SLOPE * a.z;
            a.w = a.w > 0.f ? a.w : LRELU_SLOPE * a.w;
        }
        ((float4*)out)[v] = a;
    }
}

// ---------------------------------------------------------------------------
// final head: nearest-upsample x2 + ZeroPad2d((1,0,1,0)) + Conv2d(k4,s1,p1)
// + bias + tanh, fused; all 3 output channels per thread.
// ---------------------------------------------------------------------------
__global__ __launch_bounds__(256) void final_k(
    const float* __restrict__ u, const float* __restrict__ w,
    const float* __restrict__ bias, float* __restrict__ out, int B)
{
    __shared__ float wl[3 * 64 * 16];
    const int b = blockIdx.z;
    const int tid = threadIdx.x;
    for (int i = tid; i < 3 * 64 * 16; i += 256) wl[i] = w[i];
    __syncthreads();

    const int opix = blockIdx.x * 256 + tid;  // 0..65535
    const int oy = opix >> 8, ox = opix & 255;
    const float* ib = u + (size_t)b * 64 * 128 * 128;
    float acc[3] = {bias[0], bias[1], bias[2]};

    int o[16];
    bool ok[16];
    const int r0 = (oy - 2) >> 1, r1 = (oy - 1) >> 1, r2 = oy >> 1, r3 = (oy + 1) >> 1;
    const int c0 = (ox - 2) >> 1, c1 = (ox - 1) >> 1, c2 = ox >> 1, c3 = (ox + 1) >> 1;
    const int rr[4] = {r0, r1, r2, r3};
    const int cc4[4] = {c0, c1, c2, c3};
    const bool interior = (oy >= 2 && oy <= 254 && ox >= 2 && ox <= 254);
#pragma unroll
    for (int ky = 0; ky < 4; ++ky)
#pragma unroll
        for (int kx = 0; kx < 4; ++kx) {
            const int h = oy - 2 + ky, xx = ox - 2 + kx;
            const bool v = ((unsigned)h < 256u) && ((unsigned)xx < 256u);
            ok[ky * 4 + kx] = v;
            const int rrr = v ? rr[ky] : 0, ccc = v ? cc4[kx] : 0;
            o[ky * 4 + kx] = rrr * 128 + ccc;
        }

    for (int ci = 0; ci < 64; ++ci) {
        const float* p = ib + ci * 16384;
        float v[16];
        if (interior) {
#pragma unroll
            for (int k = 0; k < 16; ++k) v[k] = p[o[k]];
        } else {
#pragma unroll
            for (int k = 0; k < 16; ++k) v[k] = ok[k] ? p[o[k]] : 0.f;
        }
#pragma unroll
        for (int co = 0; co < 3; ++co) {
            const float* wj = wl + (co * 64 + ci) * 16;
            const float4 w0 = *(const float4*)(wj + 0);
            const float4 w1 = *(const float4*)(wj + 4);
            const float4 w2 = *(const float4*)(wj + 8);
            const float4 w3 = *(const float4*)(wj + 12);
            acc[co] = fmaf(v[0], w0.x, acc[co]);  acc[co] = fmaf(v[1], w0.y, acc[co]);
            acc[co] = fmaf(v[2], w0.z, acc[co]);  acc[co] = fmaf(v[3], w0.w, acc[co]);
            acc[co] = fmaf(v[4], w1.x, acc[co]);  acc[co] = fmaf(v[5], w1.y, acc[co]);
            acc[co] = fmaf(v[6], w1.z, acc[co]);  acc[co] = fmaf(v[7], w1.w, acc[co]);
            acc[co] = fmaf(v[8], w2.x, acc[co]);  acc[co] = fmaf(v[9], w2.y, acc[co]);
            acc[co] = fmaf(v[10], w2.z, acc[co]); acc[co] = fmaf(v[11], w2.w, acc[co]);
            acc[co] = fmaf(v[12], w3.x, acc[co]); acc[co] = fmaf(v[13], w3.y, acc[co]);
            acc[co] = fmaf(v[14], w3.z, acc[co]); acc[co] = fmaf(v[15], w3.w, acc[co]);
        }
    }
#pragma unroll
    for (int co = 0; co < 3; ++co)
        out[((size_t)(b * 3 + co) * 256 + oy) * 256 + ox] = tanhf(acc[co]);
}

// ---------------------------------------------------------------------------
// DFT stage A: Rr[r,n] = sum_w U[r,w]*Wr[n,w]; Ri likewise (fused).
// ---------------------------------------------------------------------------
__global__ __launch_bounds__(256) void dft_rows_k(
    const float* __restrict__ U, const float* __restrict__ Wr,
    const float* __restrict__ Wi, float* __restrict__ Rr, float* __restrict__ Ri)
{
    __shared__ float Ut[16][17], Wrt[16][17], Wit[16][17];
    const int tx = threadIdx.x, ty = threadIdx.y;
    const int r = blockIdx.y * 16 + ty;
    const int nb = blockIdx.x * 16;
    float sr = 0.f, si = 0.f;
    for (int kk = 0; kk < 256; kk += 16) {
        Ut[ty][tx]  = U[(size_t)r * 256 + kk + tx];
        Wrt[ty][tx] = Wr[(size_t)(nb + ty) * 256 + kk + tx];
        Wit[ty][tx] = Wi[(size_t)(nb + ty) * 256 + kk + tx];
        __syncthreads();
#pragma unroll
        for (int t = 0; t < 16; ++t) {
            const float uv = Ut[ty][t];
            sr = fmaf(uv, Wrt[tx][t], sr);
            si = fmaf(uv, Wit[tx][t], si);
        }
        __syncthreads();
    }
    Rr[(size_t)r * 256 + nb + tx] = sr;
    Ri[(size_t)r * 256 + nb + tx] = si;
}

// ---------------------------------------------------------------------------
// DFT stage B (batched over bc=0..23)
// ---------------------------------------------------------------------------
__global__ __launch_bounds__(256) void dft_cols_k(
    const float* __restrict__ Wr, const float* __restrict__ Wi,
    const float* __restrict__ Rr, const float* __restrict__ Ri,
    float* __restrict__ res)
{
    __shared__ float Wrt[16][17], Wit[16][17], Rrt[16][17], Rit[16][17];
    const int tx = threadIdx.x, ty = threadIdx.y;
    const int bc = blockIdx.z;
    const int mb = blockIdx.y * 16, nb = blockIdx.x * 16;
    float cr = 0.f, ci = 0.f;
    for (int hh = 0; hh < 256; hh += 16) {
        Wrt[ty][tx] = Wr[(size_t)(hh + ty) * 256 + mb + tx];
        Wit[ty][tx] = Wi[(size_t)(hh + ty) * 256 + mb + tx];
        Rrt[ty][tx] = Rr[((size_t)bc * 256 + hh + ty) * 256 + nb + tx];
        Rit[ty][tx] = Ri[((size_t)bc * 256 + hh + ty) * 256 + nb + tx];
        __syncthreads();
#pragma unroll
        for (int t = 0; t < 16; ++t) {
            const float wr = Wrt[t][ty], wi = Wit[t][ty];
            const float rr = Rrt[t][tx], ri = Rit[t][tx];
            cr = fmaf(wr, rr, cr);  cr = fmaf(-wi, ri, cr);
            ci = fmaf(wr, ri, ci);  ci = fmaf(wi, rr, ci);
        }
        __syncthreads();
    }
    const int m = mb + ty, n = nb + tx;
    res[((size_t)bc * 256 + m) * 512 + n] = cr;
    res[((size_t)bc * 256 + m) * 512 + 256 + n] = ci;
}

// ---------------------------------------------------------------------------
// host side
// ---------------------------------------------------------------------------
static inline void take_bn(void* const* d_in, const int* in_sizes, int& i, int C,
                           const float*& g, const float*& b)
{
    if (in_sizes[i] == C) {
        g = (const float*)d_in[i];
        b = (const float*)d_in[i + 1];
        i += 2;
    } else {
        g = (const float*)d_in[i];
        b = g + C;
        i += 1;
    }
}

static inline int nblk(size_t n) { return (int)((n + 255) / 256); }
static inline size_t lds_bytes(int cich, int cob8) {
    return (size_t)cich * WROW(cob8) * 4;
}
static inline int pick_cs(int want, size_t out_elems, size_t tmp_cap) {
    int cs = want;
    while (cs > 1 && out_elems * (size_t)cs > tmp_cap) cs >>= 1;
    return cs;
}
static inline int min_i(int a, int b) { return a < b ? a : b; }

extern "C" void kernel_launch(void* const* d_in, const int* in_sizes, int n_in,
                              void* d_out, int out_size, void* d_ws, size_t ws_size,
                              hipStream_t stream)
{
    const int B = 8;
    int i = 0;
    const float* x     = (const float*)d_in[i++];
    const float* w_d1  = (const float*)d_in[i++];
    const float* w_d2  = (const float*)d_in[i++];
    const float *g_d2, *b_d2; take_bn(d_in, in_sizes, i, 128, g_d2, b_d2);
    const float* w_d3  = (const float*)d_in[i++];
    const float *g_d3, *b_d3; take_bn(d_in, in_sizes, i, 256, g_d3, b_d3);
    const float* w_d4  = (const float*)d_in[i++];
    const float *g_d4, *b_d4; take_bn(d_in, in_sizes, i, 256, g_d4, b_d4);
    const float* w_d5  = (const float*)d_in[i++];
    const float* w_u1  = (const float*)d_in[i++];
    const float *g_u1, *b_u1; take_bn(d_in, in_sizes, i, 256, g_u1, b_u1);
    const float* w_u2  = (const float*)d_in[i++];
    const float *g_u2, *b_u2; take_bn(d_in, in_sizes, i, 256, g_u2, b_u2);
    const float* w_u3  = (const float*)d_in[i++];
    const float *g_u3, *b_u3; take_bn(d_in, in_sizes, i, 128, g_u3, b_u3);
    const float* w_u4  = (const float*)d_in[i++];
    const float *g_u4, *b_u4; take_bn(d_in, in_sizes, i, 32, g_u4, b_u4);
    const float* w_fin = (const float*)d_in[i++];
    const float* b_fin = (const float*)d_in[i++];
    const float* Wr    = (const float*)d_in[i++];
    const float* Wi    = (const float*)d_in[i++];

    // ---- workspace layout (floats) ----
    float* ws = (float*)d_ws;
    size_t off = 0;
    float* u1b  = ws + off; off += (size_t)B * 512 * 16 * 16;    // 1,048,576
    float* u2b  = ws + off; off += (size_t)B * 512 * 32 * 32;    // 4,194,304
    float* u3b  = ws + off; off += (size_t)B * 256 * 64 * 64;    // 8,388,608
    float* u45b = ws + off; off += (size_t)B * 64 * 128 * 128;   // 8,388,608
    float* d5   = ws + off; off += (size_t)B * 256 * 8 * 8;      //   131,072
    float* bnm  = ws + off; off += 256;
    float* bnv  = ws + off; off += 256;
    double* part = (double*)(ws + off); off += 8192;             // 2048 pairs of doubles
    float* tmp  = ws + off;                                      // rest of ws
    size_t tmp_cap = (ws_size / 4 > off) ? (ws_size / 4 - off) : 0;
    if (tmp_cap < 4194304) tmp_cap = 4194304;  // round-5 floor (known to fit)
    if (tmp_cap > 8388608) tmp_cap = 8388608;  // max any layer wants

    float* Rr_buf = u3b;    // DFT temps alias dead decoder buffers
    float* Ri_buf = u45b;

    float* u_out = (float*)d_out;                       // [8,3,256,256]
    float* res   = u_out + (size_t)B * 3 * 256 * 256;   // [8,3,256,512]

    // per-layer split choice (want -> clamped by tmp capacity)
    const size_t oe_d2 = (size_t)B * 128 * 4096;   const int cs_d2 = pick_cs(2, oe_d2, tmp_cap);
    const size_t oe_d3 = (size_t)B * 256 * 1024;   const int cs_d3 = pick_cs(4, oe_d3, tmp_cap);
    const size_t oe_d4 = (size_t)B * 256 * 256;    const int cs_d4 = pick_cs(8, oe_d4, tmp_cap);
    const size_t oe_d5 = (size_t)B * 256 * 64;     const int cs_d5 = pick_cs(8, oe_d5, tmp_cap);
    const size_t oe_u1 = (size_t)B * 256 * 256;    const int cs_u1 = pick_cs(8, oe_u1, tmp_cap);
    const size_t oe_u2 = (size_t)B * 256 * 1024;   const int cs_u2 = pick_cs(4, oe_u2, tmp_cap);
    const size_t oe_u3 = (size_t)B * 128 * 4096;   const int cs_u3 = pick_cs(2, oe_u3, tmp_cap);
    const size_t oe_u4 = (size_t)B * 32 * 16384;   const int cs_u4 = pick_cs(2, oe_u4, tmp_cap);

    // BN helper macro: stats (2-stage) + apply
    #define BN_LAYER(C_, HW_, NB_, g_, b_, dst_, act_, Ct_, coff_, cs_, oe_)                 \
        bn_stats1_k<<<dim3(C_, NB_), 256, 0, stream>>>(tmp, part, B, C_, HW_, cs_, oe_, NB_);\
        bn_stats2_k<<<C_, 64, 0, stream>>>(part, bnm, bnv, B * HW_, NB_);                    \
        bn_act_k<<<B * C_, 256, 0, stream>>>(tmp, bnm, bnv, g_, b_, dst_, C_, HW_, act_, Ct_, coff_, cs_, oe_)

    // ---- encoder ----
    // d1 = lrelu(conv(x)) -> u45b[:,32:]  (Cin=3, no split)
    conv_down_t<4><<<dim3(16, 4, B), 256, lds_bytes(3, 8), stream>>>(
        x, w_d1, u45b, 3, 3, 256, 256, 32, 128, 128, 3, 0, 64, 32, 256, 3, 1, 1, 0);
    // d2 = lrelu(bn(conv(d1))) -> u3b[:,128:]
    {
        const int cin = 32 / cs_d2, cich = min_i(32, cin);
        conv_down_t<4><<<dim3(4, 16, B * cs_d2), 256, lds_bytes(cich, 8), stream>>>(
            u45b, w_d2, tmp, cin, 32, 128, 128, 128, 64, 64, 64, 32, 128, 0, 256, cich, 0, cs_d2, oe_d2);
        BN_LAYER(128, 4096, 16, g_d2, b_d2, u3b, 1, 256, 128, cs_d2, oe_d2);
    }
    // d3 = lrelu(bn(conv(d2))) -> u2b[:,256:]
    {
        const int cin = 128 / cs_d3, cich = min_i(32, cin);
        conv_down_t<4><<<dim3(1, 32, B * cs_d3), 256, lds_bytes(cich, 8), stream>>>(
            u3b, w_d3, tmp, cin, 128, 64, 64, 256, 32, 32, 256, 128, 256, 0, 256, cich, 0, cs_d3, oe_d3);
        BN_LAYER(256, 1024, 8, g_d3, b_d3, u2b, 1, 512, 256, cs_d3, oe_d3);
    }
    // d4 = lrelu(bn(conv(d3))) -> u1b[:,256:]
    {
        const int cin = 256 / cs_d4, cich = min_i(16, cin);
        conv_down_t<2><<<dim3(1, 16, B * cs_d4), 256, lds_bytes(cich, 16), stream>>>(
            u2b, w_d4, tmp, cin, 256, 32, 32, 256, 16, 16, 512, 256, 256, 0, 128, cich, 0, cs_d4, oe_d4);
        BN_LAYER(256, 256, 8, g_d4, b_d4, u1b, 1, 512, 256, cs_d4, oe_d4);
    }
    // d5 = lrelu(conv(d4))  (split partials -> combine_act)
    {
        const int cin = 256 / cs_d5, cich = min_i(8, cin);
        conv_down_t<1><<<dim3(1, 8, B * cs_d5), 256, lds_bytes(cich, 32), stream>>>(
            u1b, w_d5, tmp, cin, 256, 16, 16, 256, 8, 8, 512, 256, 256, 0, 64, cich, 0, cs_d5, oe_d5);
        combine_act_k<<<nblk(oe_d5 / 4), 256, 0, stream>>>(tmp, d5, oe_d5 / 4, cs_d5, oe_d5, 1);
    }

    // ---- decoder ----
    // u1 = relu(bn(convT(d5))) -> u1b[:,0:256]
    {
        const int cin = 256 / cs_u1, cich = min_i(16, cin);
        conv_up_t<2><<<dim3(1, 16, B * cs_u1), 256, lds_bytes(cich, 16), stream>>>(
            d5, w_u1, tmp, cin, 8, 8, 256, 16, 16, 256, 0, 256, 0, 128, cich, cs_u1, oe_u1);
        BN_LAYER(256, 256, 8, g_u1, b_u1, u1b, 2, 512, 0, cs_u1, oe_u1);
    }
    // u2 = relu(bn(convT(u1))) -> u2b[:,0:256]
    {
        const int cin = 512 / cs_u2, cich = min_i(32, cin);
        conv_up_t<4><<<dim3(1, 32, B * cs_u2), 256, lds_bytes(cich, 8), stream>>>(
            u1b, w_u2, tmp, cin, 16, 16, 256, 32, 32, 512, 0, 256, 0, 256, cich, cs_u2, oe_u2);
        BN_LAYER(256, 1024, 8, g_u2, b_u2, u2b, 2, 512, 0, cs_u2, oe_u2);
    }
    // u3 = relu(bn(convT(u2))) -> u3b[:,0:128]
    {
        const int cin = 512 / cs_u3, cich = min_i(32, cin);
        conv_up_t<4><<<dim3(4, 16, B * cs_u3), 256, lds_bytes(cich, 8), stream>>>(
            u2b, w_u3, tmp, cin, 32, 32, 128, 64, 64, 512, 0, 128, 0, 256, cich, cs_u3, oe_u3);
        BN_LAYER(128, 4096, 16, g_u3, b_u3, u3b, 2, 256, 0, cs_u3, oe_u3);
    }
    // u45 = relu(bn(convT(u3))) -> u45b[:,0:32]
    {
        const int cin = 256 / cs_u4, cich = min_i(32, cin);
        conv_up_t<4><<<dim3(16, 4, B * cs_u4), 256, lds_bytes(cich, 8), stream>>>(
            u3b, w_u4, tmp, cin, 64, 64, 32, 128, 128, 256, 0, 32, 0, 256, cich, cs_u4, oe_u4);
        BN_LAYER(32, 16384, 64, g_u4, b_u4, u45b, 2, 64, 0, cs_u4, oe_u4);
    }

    // ---- final head ----
    final_k<<<dim3(256, 1, B), 256, 0, stream>>>(u45b, w_fin, b_fin, u_out, B);

    // ---- DFT ----
    dft_rows_k<<<dim3(16, 384), dim3(16, 16), 0, stream>>>(u_out, Wr, Wi, Rr_buf, Ri_buf);
    dft_cols_k<<<dim3(16, 16, 24), dim3(16, 16), 0, stream>>>(Wr, Wi, Rr_buf, Ri_buf, res);

    #undef BN_LAYER
}